// Round 2
// baseline (3418.411 us; speedup 1.0000x reference)
//
#include <hip/hip_runtime.h>

#define TOK   12608
#define SLOTS 25216
#define DM    768
#define D3    2304
#define FF    3072
#define NH    12
#define SEQ   197
#define BAT   64
#define NE    8
#define VPAD  224

typedef short  short8  __attribute__((ext_vector_type(8)));
typedef float  floatx4 __attribute__((ext_vector_type(4)));

__device__ __forceinline__ unsigned short f2bf(float f) {
  union { float f; unsigned u; } c; c.f = f;
  unsigned r = c.u + 0x7fffu + ((c.u >> 16) & 1u);
  return (unsigned short)(r >> 16);
}
__device__ __forceinline__ float bf2f(unsigned short h) {
  union { unsigned u; float f; } c; c.u = ((unsigned)h) << 16; return c.f;
}

__device__ __forceinline__ void gl2lds16(const void* g, void* l) {
  __builtin_amdgcn_global_load_lds((const __attribute__((address_space(1))) unsigned int*)g,
                                   (__attribute__((address_space(3))) unsigned int*)l, 16, 0, 0);
}

// ---------------- elementwise ----------------

__global__ __launch_bounds__(256) void copy_k(float* __restrict__ dst, const float* __restrict__ src, long long n4) {
  long long i = (long long)blockIdx.x * 256 + threadIdx.x;
  long long st = (long long)gridDim.x * 256;
  for (; i < n4; i += st) ((floatx4*)dst)[i] = ((const floatx4*)src)[i];
}

__global__ __launch_bounds__(256) void conv_k(unsigned short* __restrict__ dst, const float* __restrict__ src, long long n4) {
  long long i = (long long)blockIdx.x * 256 + threadIdx.x;
  long long st = (long long)gridDim.x * 256;
  for (; i < n4; i += st) {
    floatx4 v = ((const floatx4*)src)[i];
    union { unsigned short u[4]; unsigned long long ll; } o;
    o.u[0] = f2bf(v.x); o.u[1] = f2bf(v.y); o.u[2] = f2bf(v.z); o.u[3] = f2bf(v.w);
    ((unsigned long long*)dst)[i] = o.ll;
  }
}

// hi/lo split cast
__global__ __launch_bounds__(256) void conv2_k(unsigned short* __restrict__ dhi, unsigned short* __restrict__ dlo,
                                               const float* __restrict__ src, long long n4) {
  long long i = (long long)blockIdx.x * 256 + threadIdx.x;
  long long st = (long long)gridDim.x * 256;
  for (; i < n4; i += st) {
    floatx4 v = ((const floatx4*)src)[i];
    union { unsigned short u[4]; unsigned long long ll; } oh, ol;
    #pragma unroll
    for (int j = 0; j < 4; ++j) {
      unsigned short h = f2bf(v[j]);
      oh.u[j] = h; ol.u[j] = f2bf(v[j] - bf2f(h));
    }
    ((unsigned long long*)dhi)[i] = oh.ll;
    ((unsigned long long*)dlo)[i] = ol.ll;
  }
}

__global__ void zero_k(int* p, int n) { int i = threadIdx.x; if (i < n) p[i] = 0; }

// wave-per-token layernorm -> bf16
__global__ __launch_bounds__(256) void ln_k(const float* __restrict__ x, const float* __restrict__ s,
                                            const float* __restrict__ b, unsigned short* __restrict__ out) {
  int t = blockIdx.x * 4 + (threadIdx.x >> 6);
  int lane = threadIdx.x & 63;
  const float* xr = x + (long long)t * DM;
  float v[12]; float s1 = 0.f, s2 = 0.f;
  #pragma unroll
  for (int i = 0; i < 12; ++i) { v[i] = xr[lane + i*64]; s1 += v[i]; s2 += v[i]*v[i]; }
  #pragma unroll
  for (int o = 1; o < 64; o <<= 1) { s1 += __shfl_xor(s1, o); s2 += __shfl_xor(s2, o); }
  float mu = s1 * (1.f/768.f);
  float inv = 1.f / sqrtf(s2*(1.f/768.f) - mu*mu + 1e-5f);
  unsigned short* orow = out + (long long)t * DM;
  #pragma unroll
  for (int i = 0; i < 12; ++i) { int f = lane + i*64; orow[f] = f2bf((v[i]-mu)*inv*s[f] + b[f]); }
}

// layernorm -> hi/lo bf16
__global__ __launch_bounds__(256) void ln2bf_k(const float* __restrict__ x, const float* __restrict__ s,
                                               const float* __restrict__ b, unsigned short* __restrict__ ohi,
                                               unsigned short* __restrict__ olo) {
  int t = blockIdx.x * 4 + (threadIdx.x >> 6);
  int lane = threadIdx.x & 63;
  const float* xr = x + (long long)t * DM;
  float v[12]; float s1 = 0.f, s2 = 0.f;
  #pragma unroll
  for (int i = 0; i < 12; ++i) { v[i] = xr[lane + i*64]; s1 += v[i]; s2 += v[i]*v[i]; }
  #pragma unroll
  for (int o = 1; o < 64; o <<= 1) { s1 += __shfl_xor(s1, o); s2 += __shfl_xor(s2, o); }
  float mu = s1 * (1.f/768.f);
  float inv = 1.f / sqrtf(s2*(1.f/768.f) - mu*mu + 1e-5f);
  unsigned short* rh = ohi + (long long)t * DM;
  unsigned short* rl = olo + (long long)t * DM;
  #pragma unroll
  for (int i = 0; i < 12; ++i) {
    int f = lane + i*64;
    float y = (v[i]-mu)*inv*s[f] + b[f];
    unsigned short h = f2bf(y);
    rh[f] = h; rl[f] = f2bf(y - bf2f(h));
  }
}

// fp32 LN + gating (no atomics)
__global__ __launch_bounds__(256) void gate_k(const float* __restrict__ x, const float* __restrict__ s,
    const float* __restrict__ b, const float* __restrict__ gw, float* __restrict__ logitsOut,
    int* __restrict__ e0, int* __restrict__ e1, float* __restrict__ w0, float* __restrict__ w1) {
  int t = blockIdx.x * 4 + (threadIdx.x >> 6);
  int lane = threadIdx.x & 63;
  const float* xr = x + (long long)t * DM;
  float v[12]; float s1 = 0.f, s2 = 0.f;
  #pragma unroll
  for (int i = 0; i < 12; ++i) { v[i] = xr[lane + i*64]; s1 += v[i]; s2 += v[i]*v[i]; }
  #pragma unroll
  for (int o = 1; o < 64; o <<= 1) { s1 += __shfl_xor(s1, o); s2 += __shfl_xor(s2, o); }
  float mu = s1 * (1.f/768.f);
  float inv = 1.f / sqrtf(s2*(1.f/768.f) - mu*mu + 1e-5f);
  float lg[8];
  #pragma unroll
  for (int e = 0; e < 8; ++e) lg[e] = 0.f;
  #pragma unroll
  for (int i = 0; i < 12; ++i) {
    int f = lane + i*64;
    float y = (v[i]-mu)*inv*s[f] + b[f];
    #pragma unroll
    for (int e = 0; e < 8; ++e) lg[e] += y * gw[e*DM + f];
  }
  #pragma unroll
  for (int e = 0; e < 8; ++e) {
    #pragma unroll
    for (int o = 1; o < 64; o <<= 1) lg[e] += __shfl_xor(lg[e], o);
  }
  if (lane == 0) {
    int a0 = 0;
    #pragma unroll
    for (int e = 1; e < 8; ++e) if (lg[e] > lg[a0]) a0 = e;
    int a1 = (a0 == 0) ? 1 : 0;
    #pragma unroll
    for (int e = 0; e < 8; ++e) if (e != a0 && lg[e] > lg[a1]) a1 = e;
    float mx = lg[a0];
    float pa = __expf(lg[a0]-mx), pb = __expf(lg[a1]-mx), iw = 1.f/(pa+pb);
    e0[t] = a0; e1[t] = a1; w0[t] = pa*iw; w1[t] = pb*iw;
    #pragma unroll
    for (int e = 0; e < 8; ++e) logitsOut[(long long)t*8 + e] = lg[e];
  }
}

// expert histogram
__global__ __launch_bounds__(256) void hist_k(const int* __restrict__ e0, const int* __restrict__ e1,
                                              int* __restrict__ counts) {
  __shared__ int hc[8];
  int tid = threadIdx.x;
  if (tid < 8) hc[tid] = 0;
  __syncthreads();
  int c[8];
  #pragma unroll
  for (int e = 0; e < 8; ++e) c[e] = 0;
  for (int t = blockIdx.x * 256 + tid; t < TOK; t += gridDim.x * 256) {
    int a = e0[t], b = e1[t];
    #pragma unroll
    for (int e = 0; e < 8; ++e) c[e] += (a == e) + (b == e);
  }
  #pragma unroll
  for (int e = 0; e < 8; ++e) {
    #pragma unroll
    for (int o = 1; o < 64; o <<= 1) c[e] += __shfl_xor(c[e], o);
  }
  if ((tid & 63) == 0) {
    #pragma unroll
    for (int e = 0; e < 8; ++e) atomicAdd(&hc[e], c[e]);
  }
  __syncthreads();
  if (tid < 8 && hc[tid]) atomicAdd(&counts[tid], hc[tid]);
}

// builds BOTH 128-row tiles (tileMap) and 256-row tiles (tileMap2)
__global__ void tilemap_k(const int* __restrict__ counts, int* __restrict__ cur,
                          int4* __restrict__ tileMap, int* __restrict__ tileCount,
                          int4* __restrict__ tileMap2, int* __restrict__ tileCount2) {
  if (threadIdx.x == 0 && blockIdx.x == 0) {
    int off = 0, nt = 0, n2 = 0;
    for (int e = 0; e < 8; ++e) {
      cur[e] = off;
      int cnt = counts[e];
      for (int s = 0; s < cnt; s += 128) {
        int rows = cnt - s; if (rows > 128) rows = 128;
        tileMap[nt++] = make_int4(e, off + s, rows, 0);
      }
      for (int s = 0; s < cnt; s += 256) {
        int rows = cnt - s; if (rows > 256) rows = 256;
        tileMap2[n2++] = make_int4(e, off + s, rows, 0);
      }
      off += cnt;
    }
    *tileCount = nt;
    *tileCount2 = n2;
  }
}

// wave-aggregated fetch-add scatter
__global__ __launch_bounds__(256) void scatter_k(const int* __restrict__ e0, const int* __restrict__ e1,
    const float* __restrict__ w0, const float* __restrict__ w1, int* __restrict__ cur,
    int* __restrict__ perm, float* __restrict__ wslot, int* __restrict__ slotA, int* __restrict__ slotB) {
  int t = blockIdx.x * 256 + threadIdx.x;
  int lane = threadIdx.x & 63;
  bool valid = t < TOK;
  int a = valid ? e0[t] : -1;
  int b = valid ? e1[t] : -1;
  int sa = 0, sb = 0;
  #pragma unroll
  for (int e = 0; e < 8; ++e) {
    unsigned long long m = __ballot(a == e);
    int cnt = (int)__popcll(m);
    int base = 0;
    if (lane == 0 && cnt) base = atomicAdd(&cur[e], cnt);
    base = __shfl(base, 0);
    if (a == e) sa = base + (int)__popcll(m & ((1ull << lane) - 1ull));

    unsigned long long m2 = __ballot(b == e);
    int cnt2 = (int)__popcll(m2);
    int base2 = 0;
    if (lane == 0 && cnt2) base2 = atomicAdd(&cur[e], cnt2);
    base2 = __shfl(base2, 0);
    if (b == e) sb = base2 + (int)__popcll(m2 & ((1ull << lane) - 1ull));
  }
  if (valid) {
    perm[sa] = t; wslot[sa] = w0[t]; slotA[t] = sa;
    perm[sb] = t; wslot[sb] = w1[t]; slotB[t] = sb;
  }
}

__global__ __launch_bounds__(256) void combine_k(float* __restrict__ x, const float* __restrict__ Y,
    const int* __restrict__ sA, const int* __restrict__ sB) {
  int idx = blockIdx.x * 256 + threadIdx.x;
  int t = idx / (DM/4), f = idx % (DM/4);
  const floatx4* ya = (const floatx4*)(Y + (long long)sA[t]*DM);
  const floatx4* yb = (const floatx4*)(Y + (long long)sB[t]*DM);
  floatx4* xp = (floatx4*)(x + (long long)t*DM);
  xp[f] = xp[f] + ya[f] + yb[f];
}

// V transpose (hp layer 0)
__global__ __launch_bounds__(256) void vtrans_k(const unsigned short* __restrict__ hi,
    const unsigned short* __restrict__ lo, unsigned short* __restrict__ vThi,
    unsigned short* __restrict__ vTlo) {
  __shared__ unsigned short tH[64][65], tL[64][65];
  int bh = blockIdx.x; int b = bh / NH, h = bh % NH;
  int t = threadIdx.x; int d = t & 63, sl = t >> 6;
  for (int chunk = 0; chunk < 4; ++chunk) {
    __syncthreads();
    #pragma unroll
    for (int r = 0; r < 16; ++r) {
      int sp = r*4 + sl;
      int sg = chunk*64 + sp;
      unsigned short vh = 0, vl = 0;
      if (sg < SEQ) {
        long long off = (long long)(sg*BAT + b)*D3 + 2*DM + h*64 + d;
        vh = hi[off]; vl = lo[off];
      }
      tH[sp][d] = vh; tL[sp][d] = vl;
    }
    __syncthreads();
    int s2 = t & 63, dd0 = t >> 6;
    if (chunk*64 + s2 < VPAD) {
      #pragma unroll
      for (int r = 0; r < 16; ++r) {
        int dd = r*4 + dd0;
        long long oi = ((long long)bh*64 + dd)*VPAD + chunk*64 + s2;
        vThi[oi] = tH[s2][dd];
        vTlo[oi] = tL[s2][dd];
      }
    }
  }
}

// ---------------- legacy 128x128 bf16 MFMA GEMM, BK=64 (kept for N=768 cases) ----
template<int MODE, bool GATHER, bool PERM>
__global__ __launch_bounds__(256) void gemm_k(
    const unsigned short* __restrict__ A, const unsigned short* __restrict__ Bw,
    const float* __restrict__ bias, int M, int N, int K,
    const int* __restrict__ perm, const int4* __restrict__ tileMap,
    const int* __restrict__ tileCount, const float* __restrict__ wslot,
    unsigned short* __restrict__ outB, float* __restrict__ outF,
    long long bStrideE, int biasStrideE) {
  int e = 0, rowStart, rows;
  if (GATHER) {
    if ((int)blockIdx.y >= *tileCount) return;
    int4 tm = tileMap[blockIdx.y];
    e = tm.x; rowStart = tm.y; rows = tm.z;
  } else {
    rowStart = blockIdx.y * 128;
    rows = M - rowStart; if (rows > 128) rows = 128;
  }
  __shared__ __align__(16) unsigned short As[2][128*32];
  __shared__ __align__(16) unsigned short Bs[2][128*32];
  int tid = threadIdx.x, lane = tid & 63, w = tid >> 6;
  int n0 = blockIdx.x * 128;
  const unsigned short* Bp = Bw + (long long)e * bStrideE;
  const float* biasp = bias + (long long)e * biasStrideE;

  const char* aSrc[2]; const char* bSrc[2];
  unsigned short* ldsA[2][2]; unsigned short* ldsB[2][2];
  #pragma unroll
  for (int j = 0; j < 2; ++j) {
    int row = j*64 + w*16 + (lane >> 2);
    int kb  = (lane & 3) * 16;
    int ar  = row < rows ? row : rows - 1;
    long long srcRow;
    if (GATHER) { int slot = rowStart + ar; srcRow = PERM ? (long long)perm[slot] : (long long)slot; }
    else        srcRow = rowStart + ar;
    aSrc[j] = (const char*)(A + srcRow * (long long)K) + kb;
    bSrc[j] = (const char*)(Bp + (long long)(n0 + row) * K) + kb;
    #pragma unroll
    for (int p = 0; p < 2; ++p) {
      ldsA[p][j] = &As[p][j*2048 + w*512];
      ldsB[p][j] = &Bs[p][j*2048 + w*512];
    }
  }

  floatx4 acc[4][4];
  floatx4 zf = {0.f, 0.f, 0.f, 0.f};
  #pragma unroll
  for (int i = 0; i < 4; ++i)
    #pragma unroll
    for (int j = 0; j < 4; ++j) acc[i][j] = zf;

  int wm = w >> 1, wn = w & 1;
  int aOff = (wm*64 + (lane & 15))*32 + (lane >> 4)*8;
  int bOff = (wn*64 + (lane & 15))*32 + (lane >> 4)*8;

  for (int k0 = 0; k0 < K; k0 += 64) {
    long long kb2 = (long long)k0 * 2;
    #pragma unroll
    for (int p = 0; p < 2; ++p)
      #pragma unroll
      for (int j = 0; j < 2; ++j) {
        gl2lds16(aSrc[j] + kb2 + p*64, ldsA[p][j]);
        gl2lds16(bSrc[j] + kb2 + p*64, ldsB[p][j]);
      }
    __syncthreads();
    #pragma unroll
    for (int p = 0; p < 2; ++p) {
      short8 aF[4], bF[4];
      #pragma unroll
      for (int i = 0; i < 4; ++i) aF[i] = *(const short8*)&As[p][aOff + i*512];
      #pragma unroll
      for (int j = 0; j < 4; ++j) bF[j] = *(const short8*)&Bs[p][bOff + j*512];
      #pragma unroll
      for (int i = 0; i < 4; ++i)
        #pragma unroll
        for (int j = 0; j < 4; ++j)
          acc[i][j] = __builtin_amdgcn_mfma_f32_16x16x32_bf16(aF[i], bF[j], acc[i][j], 0, 0, 0);
    }
    __syncthreads();
  }

  int quad = lane >> 4, c = lane & 15;
  #pragma unroll
  for (int i = 0; i < 4; ++i) {
    int rl0 = wm*64 + i*16 + quad*4;
    #pragma unroll
    for (int j = 0; j < 4; ++j) {
      int col = n0 + wn*64 + j*16 + c;
      float bc = biasp[col];
      #pragma unroll
      for (int r = 0; r < 4; ++r) {
        int rl = rl0 + r;
        if (rl < rows) {
          long long orow = (long long)(rowStart + rl);
          float v = acc[i][j][r] + bc;
          if (MODE == 0) {
            outB[orow*N + col] = f2bf(v);
          } else if (MODE == 1) {
            float g = v / (1.f + __expf(-1.702f * v));
            outB[orow*N + col] = f2bf(g);
          } else if (MODE == 2) {
            outF[orow*N + col] += v;
          } else {
            outF[orow*N + col] = wslot[orow] * v;
          }
        }
      }
    }
  }
}

// ---------------- 256x256 8-wave pipelined GEMM, BK=32, 4 LDS buffers, counted vmcnt ----
// waves: 2M x 4N; per-wave output 128x64; LDS 128KB; XOR bank swizzle on LDS slots.
template<int MODE, bool GATHER, bool PERM>
__global__ __launch_bounds__(512, 2) void gemm2_k(
    const unsigned short* __restrict__ A, const unsigned short* __restrict__ Bw,
    const float* __restrict__ bias, int M, int N, int K,
    const int* __restrict__ perm, const int4* __restrict__ tileMap,
    const int* __restrict__ tileCount, const float* __restrict__ wslot,
    unsigned short* __restrict__ outB, float* __restrict__ outF,
    long long bStrideE, int biasStrideE) {
  int e = 0, rowStart, rows;
  if (GATHER) {
    if ((int)blockIdx.y >= *tileCount) return;
    int4 tm = tileMap[blockIdx.y];
    e = tm.x; rowStart = tm.y; rows = tm.z;
  } else {
    rowStart = blockIdx.y * 256;
    rows = M - rowStart; if (rows > 256) rows = 256;
  }
  // buffer b at shorts b*16384: A chunk 256x32 (8192 sh), B chunk at +8192
  __shared__ __align__(16) unsigned short smem[65536];
  int tid = threadIdx.x, lane = tid & 63, w = tid >> 6;
  int wm = w >> 2, wn = w & 3;
  int n0 = blockIdx.x * 256;
  const unsigned short* Bp = Bw + (long long)e * bStrideE;
  const float* biasp = bias + (long long)e * biasStrideE;
  const int nkt = K >> 5;   // K-tiles of 32

  // ---- stage source pointers (per thread: 2 A rows + 2 B rows, fixed across K) ----
  int sRowL = w*16 + (lane >> 2);                 // 0..127
  int sSlot = (lane & 3) ^ ((lane >> 3) & 3);     // inverse-swizzled 16B slot
  long long srcA0, srcA1;
  {
    int r0 = sRowL, r1 = sRowL + 128;
    int ar0 = r0 < rows ? r0 : rows - 1;
    int ar1 = r1 < rows ? r1 : rows - 1;
    if (GATHER) {
      srcA0 = PERM ? (long long)perm[rowStart + ar0] : (long long)(rowStart + ar0);
      srcA1 = PERM ? (long long)perm[rowStart + ar1] : (long long)(rowStart + ar1);
    } else { srcA0 = rowStart + ar0; srcA1 = rowStart + ar1; }
  }
  const char* aP0 = (const char*)(A + srcA0 * (long long)K) + sSlot*16;
  const char* aP1 = (const char*)(A + srcA1 * (long long)K) + sSlot*16;
  const char* bP0 = (const char*)(Bp + (long long)(n0 + sRowL) * K) + sSlot*16;
  const char* bP1 = (const char*)(Bp + (long long)(n0 + sRowL + 128) * K) + sSlot*16;

  auto stA = [&](int tt) {
    unsigned short* l = &smem[(tt & 3)*16384 + w*512];
    long long ko = (long long)tt * 64;
    gl2lds16(aP0 + ko, l);
    gl2lds16(aP1 + ko, l + 4096);
  };
  auto stB = [&](int tt) {
    unsigned short* l = &smem[(tt & 3)*16384 + 8192 + w*512];
    long long ko = (long long)tt * 64;
    gl2lds16(bP0 + ko, l);
    gl2lds16(bP1 + ko, l + 4096);
  };

  // ---- MFMA fragment read offsets (swizzled) ----
  int laneR = lane & 15, kq = lane >> 4;
  int sx = kq ^ ((laneR >> 1) & 3);
  int aRd = (wm*128 + laneR)*32 + sx*8;           // shorts within A chunk
  int bRd = (wn*64  + laneR)*32 + sx*8;           // shorts within B chunk

  floatx4 acc[8][4];
  floatx4 zf = {0.f, 0.f, 0.f, 0.f};
  #pragma unroll
  for (int i = 0; i < 8; ++i)
    #pragma unroll
    for (int j = 0; j < 4; ++j) acc[i][j] = zf;

  // ---- prologue: stage tiles 0,1,2; wait tile 0 ----
  for (int tt = 0; tt < 3 && tt < nkt; ++tt) { stA(tt); stB(tt); }
  if (nkt > 2)      { asm volatile("s_waitcnt vmcnt(8)" ::: "memory"); }
  else if (nkt > 1) { asm volatile("s_waitcnt vmcnt(4)" ::: "memory"); }
  else              { asm volatile("s_waitcnt vmcnt(0)" ::: "memory"); }
  __builtin_amdgcn_s_barrier();

  for (int t = 0; t < nkt; ++t) {
    const int buf = (t & 3) * 16384;
    short8 aF[4], bF[4];
    // ---- phase 0: rowfrags 0..3 ----
    #pragma unroll
    for (int cf = 0; cf < 4; ++cf) bF[cf] = *(const short8*)&smem[buf + 8192 + bRd + cf*512];
    #pragma unroll
    for (int rf = 0; rf < 4; ++rf) aF[rf] = *(const short8*)&smem[buf + aRd + rf*512];
    if (t + 3 < nkt) stA(t + 3);
    asm volatile("s_waitcnt lgkmcnt(0)" ::: "memory");
    __builtin_amdgcn_sched_barrier(0);
    __builtin_amdgcn_s_setprio(1);
    #pragma unroll
    for (int rf = 0; rf < 4; ++rf)
      #pragma unroll
      for (int cf = 0; cf < 4; ++cf)
        acc[rf][cf] = __builtin_amdgcn_mfma_f32_16x16x32_bf16(aF[rf], bF[cf], acc[rf][cf], 0, 0, 0);
    __builtin_amdgcn_s_setprio(0);
    __builtin_amdgcn_s_barrier();
    // ---- phase 1: rowfrags 4..7 (reuse bF) ----
    #pragma unroll
    for (int rf = 0; rf < 4; ++rf) aF[rf] = *(const short8*)&smem[buf + aRd + (rf+4)*512];
    if (t + 3 < nkt) stB(t + 3);
    asm volatile("s_waitcnt lgkmcnt(0)" ::: "memory");
    __builtin_amdgcn_sched_barrier(0);
    __builtin_amdgcn_s_setprio(1);
    #pragma unroll
    for (int rf = 0; rf < 4; ++rf)
      #pragma unroll
      for (int cf = 0; cf < 4; ++cf)
        acc[rf+4][cf] = __builtin_amdgcn_mfma_f32_16x16x32_bf16(aF[rf], bF[cf], acc[rf+4][cf], 0, 0, 0);
    __builtin_amdgcn_s_setprio(0);
    // ---- end-of-tile: wait for tile t+1's 4 loads; keep t+2/t+3 in flight ----
    if (t + 3 < nkt)      { asm volatile("s_waitcnt vmcnt(8)" ::: "memory"); }
    else if (t + 2 < nkt) { asm volatile("s_waitcnt vmcnt(4)" ::: "memory"); }
    else if (t + 1 < nkt) { asm volatile("s_waitcnt vmcnt(0)" ::: "memory"); }
    if (t + 1 < nkt) __builtin_amdgcn_s_barrier();
  }

  // ---- epilogue ----
  #pragma unroll
  for (int rf = 0; rf < 8; ++rf) {
    int rl0 = wm*128 + rf*16 + kq*4;
    #pragma unroll
    for (int cf = 0; cf < 4; ++cf) {
      int col = n0 + wn*64 + cf*16 + laneR;
      float bc = biasp[col];
      #pragma unroll
      for (int r = 0; r < 4; ++r) {
        int rl = rl0 + r;
        if (rl < rows) {
          long long orow = (long long)(rowStart + rl);
          float v = acc[rf][cf][r] + bc;
          if (MODE == 0) {
            outB[orow*N + col] = f2bf(v);
          } else if (MODE == 1) {
            float g = v / (1.f + __expf(-1.702f * v));
            outB[orow*N + col] = f2bf(g);
          } else if (MODE == 2) {
            outF[orow*N + col] += v;
          } else {
            outF[orow*N + col] = wslot[orow] * v;
          }
        }
      }
    }
  }
}

// ---------------- split-precision (hi/lo bf16, 4-product) GEMM, BK=32 ----------------
template<int HPMODE>
__global__ __launch_bounds__(256) void gemm_hp_k(
    const unsigned short* __restrict__ Ahi, const unsigned short* __restrict__ Alo,
    const unsigned short* __restrict__ Bhi, const unsigned short* __restrict__ Blo,
    const float* __restrict__ bias, int M, int N, int K,
    unsigned short* __restrict__ oHi, unsigned short* __restrict__ oLo,
    float* __restrict__ outF) {
  int rowStart = blockIdx.y * 128;
  int rows = M - rowStart; if (rows > 128) rows = 128;
  __shared__ __align__(16) unsigned short AsH[128*32];
  __shared__ __align__(16) unsigned short AsL[128*32];
  __shared__ __align__(16) unsigned short BsH[128*32];
  __shared__ __align__(16) unsigned short BsL[128*32];
  int tid = threadIdx.x, lane = tid & 63, w = tid >> 6;
  int n0 = blockIdx.x * 128;

  const char *aH[2], *aL[2], *bH[2], *bL[2];
  unsigned short *lAH[2], *lAL[2], *lBH[2], *lBL[2];
  #pragma unroll
  for (int j = 0; j < 2; ++j) {
    int row = j*64 + w*16 + (lane >> 2);
    int kb  = (lane & 3) * 16;
    int ar  = row < rows ? row : rows - 1;
    long long srcRow = rowStart + ar;
    aH[j] = (const char*)(Ahi + srcRow * (long long)K) + kb;
    aL[j] = (const char*)(Alo + srcRow * (long long)K) + kb;
    bH[j] = (const char*)(Bhi + (long long)(n0 + row) * K) + kb;
    bL[j] = (const char*)(Blo + (long long)(n0 + row) * K) + kb;
    lAH[j] = &AsH[j*2048 + w*512]; lAL[j] = &AsL[j*2048 + w*512];
    lBH[j] = &BsH[j*2048 + w*512]; lBL[j] = &BsL[j*2048 + w*512];
  }

  floatx4 acc[4][4];
  floatx4 zf = {0.f, 0.f, 0.f, 0.f};
  #pragma unroll
  for (int i = 0; i < 4; ++i)
    #pragma unroll
    for (int j = 0; j < 4; ++j) acc[i][j] = zf;

  int wm = w >> 1, wn = w & 1;
  int aOff = (wm*64 + (lane & 15))*32 + (lane >> 4)*8;
  int bOff = (wn*64 + (lane & 15))*32 + (lane >> 4)*8;

  for (int k0 = 0; k0 < K; k0 += 32) {
    long long kb2 = (long long)k0 * 2;
    #pragma unroll
    for (int j = 0; j < 2; ++j) {
      gl2lds16(aH[j] + kb2, lAH[j]);
      gl2lds16(aL[j] + kb2, lAL[j]);
      gl2lds16(bH[j] + kb2, lBH[j]);
      gl2lds16(bL[j] + kb2, lBL[j]);
    }
    __syncthreads();
    short8 ah[4], al[4], bh[4], bl[4];
    #pragma unroll
    for (int i = 0; i < 4; ++i) {
      ah[i] = *(const short8*)&AsH[aOff + i*512];
      al[i] = *(const short8*)&AsL[aOff + i*512];
    }
    #pragma unroll
    for (int j = 0; j < 4; ++j) {
      bh[j] = *(const short8*)&BsH[bOff + j*512];
      bl[j] = *(const short8*)&BsL[bOff + j*512];
    }
    #pragma unroll
    for (int i = 0; i < 4; ++i)
      #pragma unroll
      for (int j = 0; j < 4; ++j) {
        acc[i][j] = __builtin_amdgcn_mfma_f32_16x16x32_bf16(ah[i], bh[j], acc[i][j], 0, 0, 0);
        acc[i][j] = __builtin_amdgcn_mfma_f32_16x16x32_bf16(ah[i], bl[j], acc[i][j], 0, 0, 0);
        acc[i][j] = __builtin_amdgcn_mfma_f32_16x16x32_bf16(al[i], bh[j], acc[i][j], 0, 0, 0);
        acc[i][j] = __builtin_amdgcn_mfma_f32_16x16x32_bf16(al[i], bl[j], acc[i][j], 0, 0, 0);
      }
    __syncthreads();
  }

  int quad = lane >> 4, c = lane & 15;
  #pragma unroll
  for (int i = 0; i < 4; ++i) {
    int rl0 = wm*64 + i*16 + quad*4;
    #pragma unroll
    for (int j = 0; j < 4; ++j) {
      int col = n0 + wn*64 + j*16 + c;
      float bc = bias[col];
      #pragma unroll
      for (int r = 0; r < 4; ++r) {
        int rl = rl0 + r;
        if (rl < rows) {
          long long orow = (long long)(rowStart + rl);
          float v = acc[i][j][r] + bc;
          if (HPMODE == 0) {
            unsigned short h = f2bf(v);
            oHi[orow*N + col] = h;
            oLo[orow*N + col] = f2bf(v - bf2f(h));
          } else {
            outF[orow*N + col] += v;
          }
        }
      }
    }
  }
}

// ---------------- attention (standard bf16): one block per (b,h) ----------------
__global__ __launch_bounds__(256) void attn_k(const unsigned short* __restrict__ qkv,
                                              unsigned short* __restrict__ out) {
  __shared__ __align__(16) unsigned short Vt[64*224];
  __shared__ __align__(16) unsigned short Pb[4][16*224];
  int bh = blockIdx.x; int b = bh / NH, h = bh % NH;
  int tid = threadIdx.x, lane = tid & 63, w = tid >> 6;
  for (int idx = tid; idx < 224*64; idx += 256) {
    int key = idx >> 6, d = idx & 63;
    unsigned short v = 0;
    if (key < SEQ) v = qkv[(long long)(key*BAT + b)*D3 + 2*DM + h*64 + d];
    Vt[d*224 + key] = v;
  }
  for (int idx = tid; idx < 4*16*224; idx += 256) ((unsigned short*)Pb)[idx] = 0;
  __syncthreads();

  int quad = lane >> 4, c = lane & 15;
  for (int qt = w; qt < 13; qt += 4) {
    int q0 = qt * 16;
    int qrow = q0 + c; int sq = qrow < SEQ ? qrow : SEQ-1;
    const unsigned short* qp = qkv + (long long)(sq*BAT + b)*D3 + h*64 + quad*8;
    short8 aq0 = *(const short8*)qp;
    short8 aq1 = *(const short8*)(qp + 32);
    floatx4 sc[13];
    #pragma unroll
    for (int nt = 0; nt < 13; ++nt) {
      int key = nt*16 + c; int sk = key < SEQ ? key : SEQ-1;
      const unsigned short* kp = qkv + (long long)(sk*BAT + b)*D3 + DM + h*64 + quad*8;
      short8 bk0 = *(const short8*)kp;
      short8 bk1 = *(const short8*)(kp + 32);
      floatx4 z = {0.f,0.f,0.f,0.f};
      z = __builtin_amdgcn_mfma_f32_16x16x32_bf16(aq0, bk0, z, 0, 0, 0);
      z = __builtin_amdgcn_mfma_f32_16x16x32_bf16(aq1, bk1, z, 0, 0, 0);
      sc[nt] = z;
    }
    float mx[4], sm[4];
    #pragma unroll
    for (int r = 0; r < 4; ++r) mx[r] = -1e30f;
    #pragma unroll
    for (int nt = 0; nt < 13; ++nt) {
      bool ok = (nt*16 + c) < SEQ;
      #pragma unroll
      for (int r = 0; r < 4; ++r) {
        float v = ok ? sc[nt][r] * 0.125f : -1e30f;
        sc[nt][r] = v;
        mx[r] = fmaxf(mx[r], v);
      }
    }
    #pragma unroll
    for (int r = 0; r < 4; ++r) {
      #pragma unroll
      for (int o = 1; o < 16; o <<= 1) mx[r] = fmaxf(mx[r], __shfl_xor(mx[r], o));
      sm[r] = 0.f;
    }
    #pragma unroll
    for (int nt = 0; nt < 13; ++nt) {
      #pragma unroll
      for (int r = 0; r < 4; ++r) { float p = __expf(sc[nt][r] - mx[r]); sc[nt][r] = p; sm[r] += p; }
    }
    #pragma unroll
    for (int r = 0; r < 4; ++r) {
      #pragma unroll
      for (int o = 1; o < 16; o <<= 1) sm[r] += __shfl_xor(sm[r], o);
      sm[r] = 1.f / sm[r];
    }
    #pragma unroll
    for (int nt = 0; nt < 13; ++nt) {
      #pragma unroll
      for (int r = 0; r < 4; ++r)
        Pb[w][(quad*4 + r)*224 + nt*16 + c] = f2bf(sc[nt][r] * sm[r]);
    }
    #pragma unroll
    for (int n2 = 0; n2 < 4; ++n2) {
      floatx4 o4 = {0.f,0.f,0.f,0.f};
      #pragma unroll
      for (int ks = 0; ks < 7; ++ks) {
        short8 ap = *(const short8*)&Pb[w][c*224 + ks*32 + quad*8];
        short8 bv = *(const short8*)&Vt[(n2*16 + c)*224 + ks*32 + quad*8];
        o4 = __builtin_amdgcn_mfma_f32_16x16x32_bf16(ap, bv, o4, 0, 0, 0);
      }
      #pragma unroll
      for (int r = 0; r < 4; ++r) {
        int qg = q0 + quad*4 + r;
        if (qg < SEQ)
          out[(long long)(qg*BAT + b)*DM + h*64 + n2*16 + c] = f2bf(o4[r]);
      }
    }
  }
}

// ---------------- attention, split precision (layer 0) ----------------
__global__ __launch_bounds__(256) void attn_hp_k(
    const unsigned short* __restrict__ qh, const unsigned short* __restrict__ ql,
    const unsigned short* __restrict__ vThi, const unsigned short* __restrict__ vTlo,
    unsigned short* __restrict__ oHi, unsigned short* __restrict__ oLo) {
  __shared__ __align__(16) unsigned short PbH[4][16*224];
  __shared__ __align__(16) unsigned short PbL[4][16*224];
  int bh = blockIdx.x; int b = bh / NH, h = bh % NH;
  int tid = threadIdx.x, lane = tid & 63, w = tid >> 6;
  for (int idx = lane; idx < 16*224; idx += 64) { PbH[w][idx] = 0; PbL[w][idx] = 0; }

  int quad = lane >> 4, c = lane & 15;
  const unsigned short* vHb = vThi + (long long)bh * 64 * VPAD;
  const unsigned short* vLb = vTlo + (long long)bh * 64 * VPAD;

  for (int qt = w; qt < 13; qt += 4) {
    int q0 = qt * 16;
    int qrow = q0 + c; int sq = qrow < SEQ ? qrow : SEQ-1;
    long long qoff = (long long)(sq*BAT + b)*D3 + h*64 + quad*8;
    short8 qh0 = *(const short8*)(qh + qoff);
    short8 qh1 = *(const short8*)(qh + qoff + 32);
    short8 ql0 = *(const short8*)(ql + qoff);
    short8 ql1 = *(const short8*)(ql + qoff + 32);
    floatx4 sc[13];
    #pragma unroll
    for (int nt = 0; nt < 13; ++nt) {
      int key = nt*16 + c; int sk = key < SEQ ? key : SEQ-1;
      long long koff = (long long)(sk*BAT + b)*D3 + DM + h*64 + quad*8;
      short8 kh0 = *(const short8*)(qh + koff);
      short8 kh1 = *(const short8*)(qh + koff + 32);
      short8 kl0 = *(const short8*)(ql + koff);
      short8 kl1 = *(const short8*)(ql + koff + 32);
      floatx4 z = {0.f,0.f,0.f,0.f};
      z = __builtin_amdgcn_mfma_f32_16x16x32_bf16(qh0, kh0, z, 0, 0, 0);
      z = __builtin_amdgcn_mfma_f32_16x16x32_bf16(qh0, kl0, z, 0, 0, 0);
      z = __builtin_amdgcn_mfma_f32_16x16x32_bf16(ql0, kh0, z, 0, 0, 0);
      z = __builtin_amdgcn_mfma_f32_16x16x32_bf16(ql0, kl0, z, 0, 0, 0);
      z = __builtin_amdgcn_mfma_f32_16x16x32_bf16(qh1, kh1, z, 0, 0, 0);
      z = __builtin_amdgcn_mfma_f32_16x16x32_bf16(qh1, kl1, z, 0, 0, 0);
      z = __builtin_amdgcn_mfma_f32_16x16x32_bf16(ql1, kh1, z, 0, 0, 0);
      z = __builtin_amdgcn_mfma_f32_16x16x32_bf16(ql1, kl1, z, 0, 0, 0);
      sc[nt] = z;
    }
    float mx[4], sm[4];
    #pragma unroll
    for (int r = 0; r < 4; ++r) mx[r] = -1e30f;
    #pragma unroll
    for (int nt = 0; nt < 13; ++nt) {
      bool ok = (nt*16 + c) < SEQ;
      #pragma unroll
      for (int r = 0; r < 4; ++r) {
        float v = ok ? sc[nt][r] * 0.125f : -1e30f;
        sc[nt][r] = v;
        mx[r] = fmaxf(mx[r], v);
      }
    }
    #pragma unroll
    for (int r = 0; r < 4; ++r) {
      #pragma unroll
      for (int o = 1; o < 16; o <<= 1) mx[r] = fmaxf(mx[r], __shfl_xor(mx[r], o));
      sm[r] = 0.f;
    }
    #pragma unroll
    for (int nt = 0; nt < 13; ++nt) {
      #pragma unroll
      for (int r = 0; r < 4; ++r) { float p = __expf(sc[nt][r] - mx[r]); sc[nt][r] = p; sm[r] += p; }
    }
    #pragma unroll
    for (int r = 0; r < 4; ++r) {
      #pragma unroll
      for (int o = 1; o < 16; o <<= 1) sm[r] += __shfl_xor(sm[r], o);
      sm[r] = 1.f / sm[r];
    }
    #pragma unroll
    for (int nt = 0; nt < 13; ++nt) {
      #pragma unroll
      for (int r = 0; r < 4; ++r) {
        float p = sc[nt][r] * sm[r];
        unsigned short ph = f2bf(p);
        PbH[w][(quad*4 + r)*224 + nt*16 + c] = ph;
        PbL[w][(quad*4 + r)*224 + nt*16 + c] = f2bf(p - bf2f(ph));
      }
    }
    #pragma unroll
    for (int n2 = 0; n2 < 4; ++n2) {
      floatx4 o4 = {0.f,0.f,0.f,0.f};
      const unsigned short* vh = vHb + (long long)(n2*16 + c)*VPAD;
      const unsigned short* vl = vLb + (long long)(n2*16 + c)*VPAD;
      #pragma unroll
      for (int ks = 0; ks < 7; ++ks) {
        short8 ph = *(const short8*)&PbH[w][c*224 + ks*32 + quad*8];
        short8 pl = *(const short8*)&PbL[w][c*224 + ks*32 + quad*8];
        short8 bvh = *(const short8*)(vh + ks*32 + quad*8);
        short8 bvl = *(const short8*)(vl + ks*32 + quad*8);
        o4 = __builtin_amdgcn_mfma_f32_16x16x32_bf16(ph, bvh, o4, 0, 0, 0);
        o4 = __builtin_amdgcn_mfma_f32_16x16x32_bf16(ph, bvl, o4, 0, 0, 0);
        o4 = __builtin_amdgcn_mfma_f32_16x16x32_bf16(pl, bvh, o4, 0, 0, 0);
        o4 = __builtin_amdgcn_mfma_f32_16x16x32_bf16(pl, bvl, o4, 0, 0, 0);
      }
      #pragma unroll
      for (int r = 0; r < 4; ++r) {
        int qg = q0 + quad*4 + r;
        if (qg < SEQ) {
          long long oi = (long long)(qg*BAT + b)*DM + h*64 + n2*16 + c;
          float v = o4[r];
          unsigned short hh = f2bf(v);
          oHi[oi] = hh;
          oLo[oi] = f2bf(v - bf2f(hh));
        }
      }
    }
  }
}

// ---------------- host ----------------

extern "C" void kernel_launch(void* const* d_in, const int* in_sizes, int n_in,
                              void* d_out, int out_size, void* d_ws, size_t ws_size,
                              hipStream_t stream) {
  const float* in_x    = (const float*)d_in[0];
  const float* p_mln1s = (const float*)d_in[1];
  const float* p_mln1b = (const float*)d_in[2];
  const float* p_minw  = (const float*)d_in[3];
  const float* p_minb  = (const float*)d_in[4];
  const float* p_moutw = (const float*)d_in[5];
  const float* p_moutb = (const float*)d_in[6];
  const float* p_mln2s = (const float*)d_in[7];
  const float* p_mln2b = (const float*)d_in[8];
  const float* p_gate  = (const float*)d_in[9];
  const float* p_w1    = (const float*)d_in[10];
  const float* p_b1    = (const float*)d_in[11];
  const float* p_w2    = (const float*)d_in[12];
  const float* p_b2    = (const float*)d_in[13];
  const float* p_sln1s = (const float*)d_in[14];
  const float* p_sln1b = (const float*)d_in[15];
  const float* p_sinw  = (const float*)d_in[16];
  const float* p_sinb  = (const float*)d_in[17];
  const float* p_soutw = (const float*)d_in[18];
  const float* p_soutb = (const float*)d_in[19];
  const float* p_sln2s = (const float*)d_in[20];
  const float* p_sln2b = (const float*)d_in[21];
  const float* p_sfcw  = (const float*)d_in[22];
  const float* p_sfcb  = (const float*)d_in[23];
  const float* p_sprojw= (const float*)d_in[24];
  const float* p_sprojb= (const float*)d_in[25];

  float* xout   = (float*)d_out;
  float* logits = xout + (long long)TOK * DM;

  char* wp = (char*)d_ws;
  auto carve = [&](long long bytes) -> char* {
    char* r = wp; wp += (bytes + 255) & ~255LL; return r;
  };
  unsigned short* lnB   = (unsigned short*)carve((long long)TOK * DM * 2);
  unsigned short* lnLo  = (unsigned short*)carve((long long)TOK * DM * 2);
  unsigned short* bigB  = (unsigned short*)carve((long long)SLOTS * FF * 2);  // qkvHi | Hbuf
  unsigned short* attnB = (unsigned short*)carve((long long)TOK * DM * 2);
  unsigned short* attnLo= (unsigned short*)carve((long long)TOK * DM * 2);
  float*          Ybuf  = (float*)carve((long long)SLOTS * DM * 4);           // aliases qkvLo
  unsigned short* vThi  = (unsigned short*)carve((long long)BAT*NH*64*VPAD*2 + 64);
  unsigned short* vTlo  = (unsigned short*)carve((long long)BAT*NH*64*VPAD*2 + 64);
  unsigned short* wreg  = (unsigned short*)carve(40108032LL * 2);
  unsigned short* wInLo = (unsigned short*)carve((long long)D3*DM*2);
  unsigned short* wOutLo= (unsigned short*)carve((long long)DM*DM*2);
  int*   counts   = (int*)carve(64);
  int*   cur      = (int*)carve(64);
  int*   tileCnt  = (int*)carve(64);
  int4*  tileMap  = (int4*)carve(256 * 16);
  int*   tileCnt2 = (int*)carve(64);
  int4*  tileMap2 = (int4*)carve(256 * 16);
  int*   e0 = (int*)carve(TOK*4); int* e1 = (int*)carve(TOK*4);
  float* w0 = (float*)carve(TOK*4); float* w1 = (float*)carve(TOK*4);
  int*   perm  = (int*)carve(SLOTS*4);
  float* wslot = (float*)carve(SLOTS*4);
  int*   slotA = (int*)carve(TOK*4); int* slotB = (int*)carve(TOK*4);
  (void)in_sizes; (void)n_in; (void)out_size; (void)ws_size;

  unsigned short* qkvB  = bigB;
  unsigned short* qkvLo = (unsigned short*)Ybuf;
  unsigned short* Hbuf  = bigB;
  unsigned short* wIn  = wreg;
  unsigned short* wOut = wreg + 1769472;
  unsigned short* wFc1 = wreg + 2359296;
  unsigned short* wFc2 = wreg + 21233664;

  copy_k<<<4096, 256, 0, stream>>>(xout, in_x, (long long)TOK*DM/4);

  for (int layer = 0; layer < 4; ++layer) {
    bool moe = layer < 2;
    bool hp  = (layer == 0);
    int li = moe ? layer : layer - 2;
    const float* ln1s = moe ? p_mln1s + li*DM : p_sln1s + li*DM;
    const float* ln1b = moe ? p_mln1b + li*DM : p_sln1b + li*DM;
    const float* inw  = moe ? p_minw + (long long)li*D3*DM : p_sinw + (long long)li*D3*DM;
    const float* inb  = moe ? p_minb + li*D3 : p_sinb + li*D3;
    const float* outw = moe ? p_moutw + (long long)li*DM*DM : p_soutw + (long long)li*DM*DM;
    const float* outb = moe ? p_moutb + li*DM : p_soutb + li*DM;
    const float* ln2s = moe ? p_mln2s + li*DM : p_sln2s + li*DM;
    const float* ln2b = moe ? p_mln2b + li*DM : p_sln2b + li*DM;

    if (hp) {
      conv2_k<<<2048, 256, 0, stream>>>(wIn, wInLo, inw, (long long)D3*DM/4);
      conv2_k<<<1024, 256, 0, stream>>>(wOut, wOutLo, outw, (long long)DM*DM/4);
    } else {
      conv_k<<<2048, 256, 0, stream>>>(wIn,  inw,  (long long)D3*DM/4);
      conv_k<<<1024, 256, 0, stream>>>(wOut, outw, (long long)DM*DM/4);
    }
    if (moe) {
      conv_k<<<4096, 256, 0, stream>>>(wFc1, p_w1 + (long long)li*NE*FF*DM, (long long)NE*FF*DM/4);
      conv_k<<<4096, 256, 0, stream>>>(wFc2, p_w2 + (long long)li*NE*DM*FF, (long long)NE*DM*FF/4);
    } else {
      conv_k<<<2048, 256, 0, stream>>>(wFc1, p_sfcw   + (long long)li*FF*DM, (long long)FF*DM/4);
      conv_k<<<2048, 256, 0, stream>>>(wFc2, p_sprojw + (long long)li*DM*FF, (long long)DM*FF/4);
    }

    if (hp) {
      ln2bf_k<<<TOK/4, 256, 0, stream>>>(xout, ln1s, ln1b, lnB, lnLo);
      gemm_hp_k<0><<<dim3(D3/128, 99), 256, 0, stream>>>(lnB, lnLo, wIn, wInLo, inb,
          TOK, D3, DM, qkvB, qkvLo, nullptr);
      vtrans_k<<<BAT*NH, 256, 0, stream>>>(qkvB, qkvLo, vThi, vTlo);
      attn_hp_k<<<BAT*NH, 256, 0, stream>>>(qkvB, qkvLo, vThi, vTlo, attnB, attnLo);
      gemm_hp_k<1><<<dim3(DM/128, 99), 256, 0, stream>>>(attnB, attnLo, wOut, wOutLo, outb,
          TOK, DM, DM, nullptr, nullptr, xout);
    } else {
      ln_k<<<TOK/4, 256, 0, stream>>>(xout, ln1s, ln1b, lnB);
      gemm2_k<0,false,false><<<dim3(D3/256, 50), 512, 0, stream>>>(lnB, wIn, inb, TOK, D3, DM,
          nullptr, nullptr, nullptr, nullptr, qkvB, nullptr, 0, 0);
      attn_k<<<BAT*NH, 256, 0, stream>>>(qkvB, attnB);
      gemm_k<2,false,false><<<dim3(DM/128, 99), 256, 0, stream>>>(attnB, wOut, outb, TOK, DM, DM,
          nullptr, nullptr, nullptr, nullptr, nullptr, xout, 0, 0);
    }
    ln_k<<<TOK/4, 256, 0, stream>>>(xout, ln2s, ln2b, lnB);

    if (layer == 0) {
      zero_k<<<1, 64, 0, stream>>>(counts, 8);
      gate_k<<<TOK/4, 256, 0, stream>>>(xout, ln2s, ln2b, p_gate, logits, e0, e1, w0, w1);
      hist_k<<<64, 256, 0, stream>>>(e0, e1, counts);
      tilemap_k<<<1, 1, 0, stream>>>(counts, cur, tileMap, tileCnt, tileMap2, tileCnt2);
      scatter_k<<<(TOK+255)/256, 256, 0, stream>>>(e0, e1, w0, w1, cur, perm, wslot, slotA, slotB);
    }

    if (moe) {
      gemm2_k<1,true,true><<<dim3(FF/256, 106), 512, 0, stream>>>(lnB, wFc1, p_b1 + (long long)li*NE*FF,
          SLOTS, FF, DM, perm, tileMap2, tileCnt2, nullptr, Hbuf, nullptr, (long long)FF*DM, FF);
      gemm_k<3,true,false><<<dim3(DM/128, 205), 256, 0, stream>>>(Hbuf, wFc2, p_b2 + (long long)li*NE*DM,
          SLOTS, DM, FF, nullptr, tileMap, tileCnt, wslot, nullptr, Ybuf, (long long)DM*FF, DM);
      combine_k<<<TOK*(DM/4)/256, 256, 0, stream>>>(xout, Ybuf, slotA, slotB);
    } else {
      gemm2_k<1,false,false><<<dim3(FF/256, 50), 512, 0, stream>>>(lnB, wFc1, p_sfcb + li*FF,
          TOK, FF, DM, nullptr, nullptr, nullptr, nullptr, Hbuf, nullptr, 0, 0);
      gemm_k<2,false,false><<<dim3(DM/128, 99), 256, 0, stream>>>(Hbuf, wFc2, p_sprojb + li*DM,
          TOK, DM, FF, nullptr, nullptr, nullptr, nullptr, nullptr, xout, 0, 0);
    }
  }
}

// Round 3
// 3125.771 us; speedup vs baseline: 1.0936x; 1.0936x over previous
//
#include <hip/hip_runtime.h>

#define TOK   12608
#define SLOTS 25216
#define DM    768
#define D3    2304
#define FF    3072
#define NH    12
#define SEQ   197
#define BAT   64
#define NE    8
#define VPAD  224

typedef short  short8  __attribute__((ext_vector_type(8)));
typedef float  floatx4 __attribute__((ext_vector_type(4)));

__device__ __forceinline__ unsigned short f2bf(float f) {
  union { float f; unsigned u; } c; c.f = f;
  unsigned r = c.u + 0x7fffu + ((c.u >> 16) & 1u);
  return (unsigned short)(r >> 16);
}
__device__ __forceinline__ float bf2f(unsigned short h) {
  union { unsigned u; float f; } c; c.u = ((unsigned)h) << 16; return c.f;
}

__device__ __forceinline__ void gl2lds16(const void* g, void* l) {
  __builtin_amdgcn_global_load_lds((const __attribute__((address_space(1))) unsigned int*)g,
                                   (__attribute__((address_space(3))) unsigned int*)l, 16, 0, 0);
}

// ---------------- elementwise ----------------

__global__ __launch_bounds__(256) void copy_k(float* __restrict__ dst, const float* __restrict__ src, long long n4) {
  long long i = (long long)blockIdx.x * 256 + threadIdx.x;
  long long st = (long long)gridDim.x * 256;
  for (; i < n4; i += st) ((floatx4*)dst)[i] = ((const floatx4*)src)[i];
}

__global__ __launch_bounds__(256) void conv_k(unsigned short* __restrict__ dst, const float* __restrict__ src, long long n4) {
  long long i = (long long)blockIdx.x * 256 + threadIdx.x;
  long long st = (long long)gridDim.x * 256;
  for (; i < n4; i += st) {
    floatx4 v = ((const floatx4*)src)[i];
    union { unsigned short u[4]; unsigned long long ll; } o;
    o.u[0] = f2bf(v.x); o.u[1] = f2bf(v.y); o.u[2] = f2bf(v.z); o.u[3] = f2bf(v.w);
    ((unsigned long long*)dst)[i] = o.ll;
  }
}

// hi/lo split cast
__global__ __launch_bounds__(256) void conv2_k(unsigned short* __restrict__ dhi, unsigned short* __restrict__ dlo,
                                               const float* __restrict__ src, long long n4) {
  long long i = (long long)blockIdx.x * 256 + threadIdx.x;
  long long st = (long long)gridDim.x * 256;
  for (; i < n4; i += st) {
    floatx4 v = ((const floatx4*)src)[i];
    union { unsigned short u[4]; unsigned long long ll; } oh, ol;
    #pragma unroll
    for (int j = 0; j < 4; ++j) {
      unsigned short h = f2bf(v[j]);
      oh.u[j] = h; ol.u[j] = f2bf(v[j] - bf2f(h));
    }
    ((unsigned long long*)dhi)[i] = oh.ll;
    ((unsigned long long*)dlo)[i] = ol.ll;
  }
}

__global__ void zero_k(int* p, int n) { int i = threadIdx.x; if (i < n) p[i] = 0; }

// wave-per-token layernorm -> bf16
__global__ __launch_bounds__(256) void ln_k(const float* __restrict__ x, const float* __restrict__ s,
                                            const float* __restrict__ b, unsigned short* __restrict__ out) {
  int t = blockIdx.x * 4 + (threadIdx.x >> 6);
  int lane = threadIdx.x & 63;
  const float* xr = x + (long long)t * DM;
  float v[12]; float s1 = 0.f, s2 = 0.f;
  #pragma unroll
  for (int i = 0; i < 12; ++i) { v[i] = xr[lane + i*64]; s1 += v[i]; s2 += v[i]*v[i]; }
  #pragma unroll
  for (int o = 1; o < 64; o <<= 1) { s1 += __shfl_xor(s1, o); s2 += __shfl_xor(s2, o); }
  float mu = s1 * (1.f/768.f);
  float inv = 1.f / sqrtf(s2*(1.f/768.f) - mu*mu + 1e-5f);
  unsigned short* orow = out + (long long)t * DM;
  #pragma unroll
  for (int i = 0; i < 12; ++i) { int f = lane + i*64; orow[f] = f2bf((v[i]-mu)*inv*s[f] + b[f]); }
}

// layernorm -> hi/lo bf16
__global__ __launch_bounds__(256) void ln2bf_k(const float* __restrict__ x, const float* __restrict__ s,
                                               const float* __restrict__ b, unsigned short* __restrict__ ohi,
                                               unsigned short* __restrict__ olo) {
  int t = blockIdx.x * 4 + (threadIdx.x >> 6);
  int lane = threadIdx.x & 63;
  const float* xr = x + (long long)t * DM;
  float v[12]; float s1 = 0.f, s2 = 0.f;
  #pragma unroll
  for (int i = 0; i < 12; ++i) { v[i] = xr[lane + i*64]; s1 += v[i]; s2 += v[i]*v[i]; }
  #pragma unroll
  for (int o = 1; o < 64; o <<= 1) { s1 += __shfl_xor(s1, o); s2 += __shfl_xor(s2, o); }
  float mu = s1 * (1.f/768.f);
  float inv = 1.f / sqrtf(s2*(1.f/768.f) - mu*mu + 1e-5f);
  unsigned short* rh = ohi + (long long)t * DM;
  unsigned short* rl = olo + (long long)t * DM;
  #pragma unroll
  for (int i = 0; i < 12; ++i) {
    int f = lane + i*64;
    float y = (v[i]-mu)*inv*s[f] + b[f];
    unsigned short h = f2bf(y);
    rh[f] = h; rl[f] = f2bf(y - bf2f(h));
  }
}

// fp32 LN + gating (no atomics)
__global__ __launch_bounds__(256) void gate_k(const float* __restrict__ x, const float* __restrict__ s,
    const float* __restrict__ b, const float* __restrict__ gw, float* __restrict__ logitsOut,
    int* __restrict__ e0, int* __restrict__ e1, float* __restrict__ w0, float* __restrict__ w1) {
  int t = blockIdx.x * 4 + (threadIdx.x >> 6);
  int lane = threadIdx.x & 63;
  const float* xr = x + (long long)t * DM;
  float v[12]; float s1 = 0.f, s2 = 0.f;
  #pragma unroll
  for (int i = 0; i < 12; ++i) { v[i] = xr[lane + i*64]; s1 += v[i]; s2 += v[i]*v[i]; }
  #pragma unroll
  for (int o = 1; o < 64; o <<= 1) { s1 += __shfl_xor(s1, o); s2 += __shfl_xor(s2, o); }
  float mu = s1 * (1.f/768.f);
  float inv = 1.f / sqrtf(s2*(1.f/768.f) - mu*mu + 1e-5f);
  float lg[8];
  #pragma unroll
  for (int e = 0; e < 8; ++e) lg[e] = 0.f;
  #pragma unroll
  for (int i = 0; i < 12; ++i) {
    int f = lane + i*64;
    float y = (v[i]-mu)*inv*s[f] + b[f];
    #pragma unroll
    for (int e = 0; e < 8; ++e) lg[e] += y * gw[e*DM + f];
  }
  #pragma unroll
  for (int e = 0; e < 8; ++e) {
    #pragma unroll
    for (int o = 1; o < 64; o <<= 1) lg[e] += __shfl_xor(lg[e], o);
  }
  if (lane == 0) {
    int a0 = 0;
    #pragma unroll
    for (int e = 1; e < 8; ++e) if (lg[e] > lg[a0]) a0 = e;
    int a1 = (a0 == 0) ? 1 : 0;
    #pragma unroll
    for (int e = 0; e < 8; ++e) if (e != a0 && lg[e] > lg[a1]) a1 = e;
    float mx = lg[a0];
    float pa = __expf(lg[a0]-mx), pb = __expf(lg[a1]-mx), iw = 1.f/(pa+pb);
    e0[t] = a0; e1[t] = a1; w0[t] = pa*iw; w1[t] = pb*iw;
    #pragma unroll
    for (int e = 0; e < 8; ++e) logitsOut[(long long)t*8 + e] = lg[e];
  }
}

// expert histogram
__global__ __launch_bounds__(256) void hist_k(const int* __restrict__ e0, const int* __restrict__ e1,
                                              int* __restrict__ counts) {
  __shared__ int hc[8];
  int tid = threadIdx.x;
  if (tid < 8) hc[tid] = 0;
  __syncthreads();
  int c[8];
  #pragma unroll
  for (int e = 0; e < 8; ++e) c[e] = 0;
  for (int t = blockIdx.x * 256 + tid; t < TOK; t += gridDim.x * 256) {
    int a = e0[t], b = e1[t];
    #pragma unroll
    for (int e = 0; e < 8; ++e) c[e] += (a == e) + (b == e);
  }
  #pragma unroll
  for (int e = 0; e < 8; ++e) {
    #pragma unroll
    for (int o = 1; o < 64; o <<= 1) c[e] += __shfl_xor(c[e], o);
  }
  if ((tid & 63) == 0) {
    #pragma unroll
    for (int e = 0; e < 8; ++e) atomicAdd(&hc[e], c[e]);
  }
  __syncthreads();
  if (tid < 8 && hc[tid]) atomicAdd(&counts[tid], hc[tid]);
}

__global__ void tilemap_k(const int* __restrict__ counts, int* __restrict__ cur,
                          int4* __restrict__ tileMap, int* __restrict__ tileCount) {
  if (threadIdx.x == 0 && blockIdx.x == 0) {
    int off = 0, nt = 0;
    for (int e = 0; e < 8; ++e) {
      cur[e] = off;
      int cnt = counts[e];
      for (int s = 0; s < cnt; s += 128) {
        int rows = cnt - s; if (rows > 128) rows = 128;
        tileMap[nt++] = make_int4(e, off + s, rows, 0);
      }
      off += cnt;
    }
    *tileCount = nt;
  }
}

// wave-aggregated fetch-add scatter
__global__ __launch_bounds__(256) void scatter_k(const int* __restrict__ e0, const int* __restrict__ e1,
    const float* __restrict__ w0, const float* __restrict__ w1, int* __restrict__ cur,
    int* __restrict__ perm, float* __restrict__ wslot, int* __restrict__ slotA, int* __restrict__ slotB) {
  int t = blockIdx.x * 256 + threadIdx.x;
  int lane = threadIdx.x & 63;
  bool valid = t < TOK;
  int a = valid ? e0[t] : -1;
  int b = valid ? e1[t] : -1;
  int sa = 0, sb = 0;
  #pragma unroll
  for (int e = 0; e < 8; ++e) {
    unsigned long long m = __ballot(a == e);
    int cnt = (int)__popcll(m);
    int base = 0;
    if (lane == 0 && cnt) base = atomicAdd(&cur[e], cnt);
    base = __shfl(base, 0);
    if (a == e) sa = base + (int)__popcll(m & ((1ull << lane) - 1ull));

    unsigned long long m2 = __ballot(b == e);
    int cnt2 = (int)__popcll(m2);
    int base2 = 0;
    if (lane == 0 && cnt2) base2 = atomicAdd(&cur[e], cnt2);
    base2 = __shfl(base2, 0);
    if (b == e) sb = base2 + (int)__popcll(m2 & ((1ull << lane) - 1ull));
  }
  if (valid) {
    perm[sa] = t; wslot[sa] = w0[t]; slotA[t] = sa;
    perm[sb] = t; wslot[sb] = w1[t]; slotB[t] = sb;
  }
}

__global__ __launch_bounds__(256) void combine_k(float* __restrict__ x, const float* __restrict__ Y,
    const int* __restrict__ sA, const int* __restrict__ sB) {
  int idx = blockIdx.x * 256 + threadIdx.x;
  int t = idx / (DM/4), f = idx % (DM/4);
  const floatx4* ya = (const floatx4*)(Y + (long long)sA[t]*DM);
  const floatx4* yb = (const floatx4*)(Y + (long long)sB[t]*DM);
  floatx4* xp = (floatx4*)(x + (long long)t*DM);
  xp[f] = xp[f] + ya[f] + yb[f];
}

// V transpose (hp layer 0)
__global__ __launch_bounds__(256) void vtrans_k(const unsigned short* __restrict__ hi,
    const unsigned short* __restrict__ lo, unsigned short* __restrict__ vThi,
    unsigned short* __restrict__ vTlo) {
  __shared__ unsigned short tH[64][65], tL[64][65];
  int bh = blockIdx.x; int b = bh / NH, h = bh % NH;
  int t = threadIdx.x; int d = t & 63, sl = t >> 6;
  for (int chunk = 0; chunk < 4; ++chunk) {
    __syncthreads();
    #pragma unroll
    for (int r = 0; r < 16; ++r) {
      int sp = r*4 + sl;
      int sg = chunk*64 + sp;
      unsigned short vh = 0, vl = 0;
      if (sg < SEQ) {
        long long off = (long long)(sg*BAT + b)*D3 + 2*DM + h*64 + d;
        vh = hi[off]; vl = lo[off];
      }
      tH[sp][d] = vh; tL[sp][d] = vl;
    }
    __syncthreads();
    int s2 = t & 63, dd0 = t >> 6;
    if (chunk*64 + s2 < VPAD) {
      #pragma unroll
      for (int r = 0; r < 16; ++r) {
        int dd = r*4 + dd0;
        long long oi = ((long long)bh*64 + dd)*VPAD + chunk*64 + s2;
        vThi[oi] = tH[s2][dd];
        vTlo[oi] = tL[s2][dd];
      }
    }
  }
}

// ---------------- 128x128 bf16 MFMA GEMM, BK=64 ----------------
// Swapped-operand MFMA: mfma(bF, aF, acc) transposes the C fragment so each lane
// holds 4 CONSECUTIVE COLUMNS of one output row -> 8B/16B vector stores.
// acc[i][j]: row = wm*64 + i*16 + (lane&15); cols = n0 + wn*64 + j*16 + (lane>>4)*4 + r
template<int MODE, bool GATHER, bool PERM>
__global__ __launch_bounds__(256) void gemm_k(
    const unsigned short* __restrict__ A, const unsigned short* __restrict__ Bw,
    const float* __restrict__ bias, int M, int N, int K,
    const int* __restrict__ perm, const int4* __restrict__ tileMap,
    const int* __restrict__ tileCount, const float* __restrict__ wslot,
    unsigned short* __restrict__ outB, float* __restrict__ outF,
    long long bStrideE, int biasStrideE) {
  int e = 0, rowStart, rows;
  if (GATHER) {
    if ((int)blockIdx.y >= *tileCount) return;
    int4 tm = tileMap[blockIdx.y];
    e = tm.x; rowStart = tm.y; rows = tm.z;
  } else {
    rowStart = blockIdx.y * 128;
    rows = M - rowStart; if (rows > 128) rows = 128;
  }
  __shared__ __align__(16) unsigned short As[2][128*32];
  __shared__ __align__(16) unsigned short Bs[2][128*32];
  int tid = threadIdx.x, lane = tid & 63, w = tid >> 6;
  int n0 = blockIdx.x * 128;
  const unsigned short* Bp = Bw + (long long)e * bStrideE;
  const float* biasp = bias + (long long)e * biasStrideE;

  const char* aSrc[2]; const char* bSrc[2];
  unsigned short* ldsA[2][2]; unsigned short* ldsB[2][2];
  #pragma unroll
  for (int j = 0; j < 2; ++j) {
    int row = j*64 + w*16 + (lane >> 2);
    int kb  = (lane & 3) * 16;
    int ar  = row < rows ? row : rows - 1;
    long long srcRow;
    if (GATHER) { int slot = rowStart + ar; srcRow = PERM ? (long long)perm[slot] : (long long)slot; }
    else        srcRow = rowStart + ar;
    aSrc[j] = (const char*)(A + srcRow * (long long)K) + kb;
    bSrc[j] = (const char*)(Bp + (long long)(n0 + row) * K) + kb;
    #pragma unroll
    for (int p = 0; p < 2; ++p) {
      ldsA[p][j] = &As[p][j*2048 + w*512];
      ldsB[p][j] = &Bs[p][j*2048 + w*512];
    }
  }

  floatx4 acc[4][4];
  floatx4 zf = {0.f, 0.f, 0.f, 0.f};
  #pragma unroll
  for (int i = 0; i < 4; ++i)
    #pragma unroll
    for (int j = 0; j < 4; ++j) acc[i][j] = zf;

  int wm = w >> 1, wn = w & 1;
  int aOff = (wm*64 + (lane & 15))*32 + (lane >> 4)*8;
  int bOff = (wn*64 + (lane & 15))*32 + (lane >> 4)*8;

  for (int k0 = 0; k0 < K; k0 += 64) {
    long long kb2 = (long long)k0 * 2;
    #pragma unroll
    for (int p = 0; p < 2; ++p)
      #pragma unroll
      for (int j = 0; j < 2; ++j) {
        gl2lds16(aSrc[j] + kb2 + p*64, ldsA[p][j]);
        gl2lds16(bSrc[j] + kb2 + p*64, ldsB[p][j]);
      }
    __syncthreads();
    #pragma unroll
    for (int p = 0; p < 2; ++p) {
      short8 aF[4], bF[4];
      #pragma unroll
      for (int i = 0; i < 4; ++i) aF[i] = *(const short8*)&As[p][aOff + i*512];
      #pragma unroll
      for (int j = 0; j < 4; ++j) bF[j] = *(const short8*)&Bs[p][bOff + j*512];
      #pragma unroll
      for (int i = 0; i < 4; ++i)
        #pragma unroll
        for (int j = 0; j < 4; ++j)
          acc[i][j] = __builtin_amdgcn_mfma_f32_16x16x32_bf16(bF[j], aF[i], acc[i][j], 0, 0, 0);
    }
    __syncthreads();
  }

  int c = lane & 15, quad = lane >> 4;
  #pragma unroll
  for (int i = 0; i < 4; ++i) {
    int rl = wm*64 + i*16 + c;
    if (rl < rows) {
      long long orow = (long long)(rowStart + rl);
      float ws = (MODE == 3) ? wslot[orow] : 0.f;
      #pragma unroll
      for (int j = 0; j < 4; ++j) {
        int col = n0 + wn*64 + j*16 + quad*4;
        floatx4 bc4 = *(const floatx4*)&biasp[col];
        floatx4 v4;
        #pragma unroll
        for (int r = 0; r < 4; ++r) v4[r] = acc[i][j][r] + bc4[r];
        if (MODE == 0) {
          union { unsigned short u[4]; unsigned long long ll; } o;
          #pragma unroll
          for (int r = 0; r < 4; ++r) o.u[r] = f2bf(v4[r]);
          *(unsigned long long*)&outB[orow*N + col] = o.ll;
        } else if (MODE == 1) {
          union { unsigned short u[4]; unsigned long long ll; } o;
          #pragma unroll
          for (int r = 0; r < 4; ++r) {
            float g = v4[r] / (1.f + __expf(-1.702f * v4[r]));
            o.u[r] = f2bf(g);
          }
          *(unsigned long long*)&outB[orow*N + col] = o.ll;
        } else if (MODE == 2) {
          floatx4* op = (floatx4*)&outF[orow*N + col];
          *op = *op + v4;
        } else {
          floatx4 sv;
          #pragma unroll
          for (int r = 0; r < 4; ++r) sv[r] = ws * v4[r];
          *(floatx4*)&outF[orow*N + col] = sv;
        }
      }
    }
  }
}

// ---------------- split-precision (hi/lo bf16, 3-product) GEMM, BK=32 ----------------
template<int HPMODE>
__global__ __launch_bounds__(256) void gemm_hp_k(
    const unsigned short* __restrict__ Ahi, const unsigned short* __restrict__ Alo,
    const unsigned short* __restrict__ Bhi, const unsigned short* __restrict__ Blo,
    const float* __restrict__ bias, int M, int N, int K,
    unsigned short* __restrict__ oHi, unsigned short* __restrict__ oLo,
    float* __restrict__ outF) {
  int rowStart = blockIdx.y * 128;
  int rows = M - rowStart; if (rows > 128) rows = 128;
  __shared__ __align__(16) unsigned short AsH[128*32];
  __shared__ __align__(16) unsigned short AsL[128*32];
  __shared__ __align__(16) unsigned short BsH[128*32];
  __shared__ __align__(16) unsigned short BsL[128*32];
  int tid = threadIdx.x, lane = tid & 63, w = tid >> 6;
  int n0 = blockIdx.x * 128;

  const char *aH[2], *aL[2], *bH[2], *bL[2];
  unsigned short *lAH[2], *lAL[2], *lBH[2], *lBL[2];
  #pragma unroll
  for (int j = 0; j < 2; ++j) {
    int row = j*64 + w*16 + (lane >> 2);
    int kb  = (lane & 3) * 16;
    int ar  = row < rows ? row : rows - 1;
    long long srcRow = rowStart + ar;
    aH[j] = (const char*)(Ahi + srcRow * (long long)K) + kb;
    aL[j] = (const char*)(Alo + srcRow * (long long)K) + kb;
    bH[j] = (const char*)(Bhi + (long long)(n0 + row) * K) + kb;
    bL[j] = (const char*)(Blo + (long long)(n0 + row) * K) + kb;
    lAH[j] = &AsH[j*2048 + w*512]; lAL[j] = &AsL[j*2048 + w*512];
    lBH[j] = &BsH[j*2048 + w*512]; lBL[j] = &BsL[j*2048 + w*512];
  }

  floatx4 acc[4][4];
  floatx4 zf = {0.f, 0.f, 0.f, 0.f};
  #pragma unroll
  for (int i = 0; i < 4; ++i)
    #pragma unroll
    for (int j = 0; j < 4; ++j) acc[i][j] = zf;

  int wm = w >> 1, wn = w & 1;
  int aOff = (wm*64 + (lane & 15))*32 + (lane >> 4)*8;
  int bOff = (wn*64 + (lane & 15))*32 + (lane >> 4)*8;

  for (int k0 = 0; k0 < K; k0 += 32) {
    long long kb2 = (long long)k0 * 2;
    #pragma unroll
    for (int j = 0; j < 2; ++j) {
      gl2lds16(aH[j] + kb2, lAH[j]);
      gl2lds16(aL[j] + kb2, lAL[j]);
      gl2lds16(bH[j] + kb2, lBH[j]);
      gl2lds16(bL[j] + kb2, lBL[j]);
    }
    __syncthreads();
    short8 ah[4], al[4], bh[4], bl[4];
    #pragma unroll
    for (int i = 0; i < 4; ++i) {
      ah[i] = *(const short8*)&AsH[aOff + i*512];
      al[i] = *(const short8*)&AsL[aOff + i*512];
    }
    #pragma unroll
    for (int j = 0; j < 4; ++j) {
      bh[j] = *(const short8*)&BsH[bOff + j*512];
      bl[j] = *(const short8*)&BsL[bOff + j*512];
    }
    #pragma unroll
    for (int i = 0; i < 4; ++i)
      #pragma unroll
      for (int j = 0; j < 4; ++j) {
        acc[i][j] = __builtin_amdgcn_mfma_f32_16x16x32_bf16(bh[j], ah[i], acc[i][j], 0, 0, 0);
        acc[i][j] = __builtin_amdgcn_mfma_f32_16x16x32_bf16(bl[j], ah[i], acc[i][j], 0, 0, 0);
        acc[i][j] = __builtin_amdgcn_mfma_f32_16x16x32_bf16(bh[j], al[i], acc[i][j], 0, 0, 0);
      }
    __syncthreads();
  }

  int c = lane & 15, quad = lane >> 4;
  #pragma unroll
  for (int i = 0; i < 4; ++i) {
    int rl = wm*64 + i*16 + c;
    if (rl < rows) {
      long long orow = (long long)(rowStart + rl);
      #pragma unroll
      for (int j = 0; j < 4; ++j) {
        int col = n0 + wn*64 + j*16 + quad*4;
        floatx4 bc4 = *(const floatx4*)&bias[col];
        floatx4 v4;
        #pragma unroll
        for (int r = 0; r < 4; ++r) v4[r] = acc[i][j][r] + bc4[r];
        if (HPMODE == 0) {
          union { unsigned short u[4]; unsigned long long ll; } oh, ol;
          #pragma unroll
          for (int r = 0; r < 4; ++r) {
            unsigned short h = f2bf(v4[r]);
            oh.u[r] = h; ol.u[r] = f2bf(v4[r] - bf2f(h));
          }
          *(unsigned long long*)&oHi[orow*N + col] = oh.ll;
          *(unsigned long long*)&oLo[orow*N + col] = ol.ll;
        } else {
          floatx4* op = (floatx4*)&outF[orow*N + col];
          *op = *op + v4;
        }
      }
    }
  }
}

// ---------------- attention (standard bf16): one block per (b,h) ----------------
__global__ __launch_bounds__(256) void attn_k(const unsigned short* __restrict__ qkv,
                                              unsigned short* __restrict__ out) {
  __shared__ __align__(16) unsigned short Vt[64*224];
  __shared__ __align__(16) unsigned short Pb[4][16*224];
  int bh = blockIdx.x; int b = bh / NH, h = bh % NH;
  int tid = threadIdx.x, lane = tid & 63, w = tid >> 6;
  for (int idx = tid; idx < 224*64; idx += 256) {
    int key = idx >> 6, d = idx & 63;
    unsigned short v = 0;
    if (key < SEQ) v = qkv[(long long)(key*BAT + b)*D3 + 2*DM + h*64 + d];
    Vt[d*224 + key] = v;
  }
  for (int idx = tid; idx < 4*16*224; idx += 256) ((unsigned short*)Pb)[idx] = 0;
  __syncthreads();

  int quad = lane >> 4, c = lane & 15;
  for (int qt = w; qt < 13; qt += 4) {
    int q0 = qt * 16;
    int qrow = q0 + c; int sq = qrow < SEQ ? qrow : SEQ-1;
    const unsigned short* qp = qkv + (long long)(sq*BAT + b)*D3 + h*64 + quad*8;
    short8 aq0 = *(const short8*)qp;
    short8 aq1 = *(const short8*)(qp + 32);
    floatx4 sc[13];
    #pragma unroll
    for (int nt = 0; nt < 13; ++nt) {
      int key = nt*16 + c; int sk = key < SEQ ? key : SEQ-1;
      const unsigned short* kp = qkv + (long long)(sk*BAT + b)*D3 + DM + h*64 + quad*8;
      short8 bk0 = *(const short8*)kp;
      short8 bk1 = *(const short8*)(kp + 32);
      floatx4 z = {0.f,0.f,0.f,0.f};
      z = __builtin_amdgcn_mfma_f32_16x16x32_bf16(aq0, bk0, z, 0, 0, 0);
      z = __builtin_amdgcn_mfma_f32_16x16x32_bf16(aq1, bk1, z, 0, 0, 0);
      sc[nt] = z;
    }
    float mx[4], sm[4];
    #pragma unroll
    for (int r = 0; r < 4; ++r) mx[r] = -1e30f;
    #pragma unroll
    for (int nt = 0; nt < 13; ++nt) {
      bool ok = (nt*16 + c) < SEQ;
      #pragma unroll
      for (int r = 0; r < 4; ++r) {
        float v = ok ? sc[nt][r] * 0.125f : -1e30f;
        sc[nt][r] = v;
        mx[r] = fmaxf(mx[r], v);
      }
    }
    #pragma unroll
    for (int r = 0; r < 4; ++r) {
      #pragma unroll
      for (int o = 1; o < 16; o <<= 1) mx[r] = fmaxf(mx[r], __shfl_xor(mx[r], o));
      sm[r] = 0.f;
    }
    #pragma unroll
    for (int nt = 0; nt < 13; ++nt) {
      #pragma unroll
      for (int r = 0; r < 4; ++r) { float p = __expf(sc[nt][r] - mx[r]); sc[nt][r] = p; sm[r] += p; }
    }
    #pragma unroll
    for (int r = 0; r < 4; ++r) {
      #pragma unroll
      for (int o = 1; o < 16; o <<= 1) sm[r] += __shfl_xor(sm[r], o);
      sm[r] = 1.f / sm[r];
    }
    #pragma unroll
    for (int nt = 0; nt < 13; ++nt) {
      #pragma unroll
      for (int r = 0; r < 4; ++r)
        Pb[w][(quad*4 + r)*224 + nt*16 + c] = f2bf(sc[nt][r] * sm[r]);
    }
    #pragma unroll
    for (int n2 = 0; n2 < 4; ++n2) {
      floatx4 o4 = {0.f,0.f,0.f,0.f};
      #pragma unroll
      for (int ks = 0; ks < 7; ++ks) {
        short8 ap = *(const short8*)&Pb[w][c*224 + ks*32 + quad*8];
        short8 bv = *(const short8*)&Vt[(n2*16 + c)*224 + ks*32 + quad*8];
        o4 = __builtin_amdgcn_mfma_f32_16x16x32_bf16(ap, bv, o4, 0, 0, 0);
      }
      #pragma unroll
      for (int r = 0; r < 4; ++r) {
        int qg = q0 + quad*4 + r;
        if (qg < SEQ)
          out[(long long)(qg*BAT + b)*DM + h*64 + n2*16 + c] = f2bf(o4[r]);
      }
    }
  }
}

// ---------------- attention, split precision 3-product (layer 0) ----------------
__global__ __launch_bounds__(256) void attn_hp_k(
    const unsigned short* __restrict__ qh, const unsigned short* __restrict__ ql,
    const unsigned short* __restrict__ vThi, const unsigned short* __restrict__ vTlo,
    unsigned short* __restrict__ oHi, unsigned short* __restrict__ oLo) {
  __shared__ __align__(16) unsigned short PbH[4][16*224];
  __shared__ __align__(16) unsigned short PbL[4][16*224];
  int bh = blockIdx.x; int b = bh / NH, h = bh % NH;
  int tid = threadIdx.x, lane = tid & 63, w = tid >> 6;
  for (int idx = lane; idx < 16*224; idx += 64) { PbH[w][idx] = 0; PbL[w][idx] = 0; }

  int quad = lane >> 4, c = lane & 15;
  const unsigned short* vHb = vThi + (long long)bh * 64 * VPAD;
  const unsigned short* vLb = vTlo + (long long)bh * 64 * VPAD;

  for (int qt = w; qt < 13; qt += 4) {
    int q0 = qt * 16;
    int qrow = q0 + c; int sq = qrow < SEQ ? qrow : SEQ-1;
    long long qoff = (long long)(sq*BAT + b)*D3 + h*64 + quad*8;
    short8 qh0 = *(const short8*)(qh + qoff);
    short8 qh1 = *(const short8*)(qh + qoff + 32);
    short8 ql0 = *(const short8*)(ql + qoff);
    short8 ql1 = *(const short8*)(ql + qoff + 32);
    floatx4 sc[13];
    #pragma unroll
    for (int nt = 0; nt < 13; ++nt) {
      int key = nt*16 + c; int sk = key < SEQ ? key : SEQ-1;
      long long koff = (long long)(sk*BAT + b)*D3 + DM + h*64 + quad*8;
      short8 kh0 = *(const short8*)(qh + koff);
      short8 kh1 = *(const short8*)(qh + koff + 32);
      short8 kl0 = *(const short8*)(ql + koff);
      short8 kl1 = *(const short8*)(ql + koff + 32);
      floatx4 z = {0.f,0.f,0.f,0.f};
      z = __builtin_amdgcn_mfma_f32_16x16x32_bf16(qh0, kh0, z, 0, 0, 0);
      z = __builtin_amdgcn_mfma_f32_16x16x32_bf16(qh0, kl0, z, 0, 0, 0);
      z = __builtin_amdgcn_mfma_f32_16x16x32_bf16(ql0, kh0, z, 0, 0, 0);
      z = __builtin_amdgcn_mfma_f32_16x16x32_bf16(qh1, kh1, z, 0, 0, 0);
      z = __builtin_amdgcn_mfma_f32_16x16x32_bf16(qh1, kl1, z, 0, 0, 0);
      z = __builtin_amdgcn_mfma_f32_16x16x32_bf16(ql1, kh1, z, 0, 0, 0);
      sc[nt] = z;
    }
    float mx[4], sm[4];
    #pragma unroll
    for (int r = 0; r < 4; ++r) mx[r] = -1e30f;
    #pragma unroll
    for (int nt = 0; nt < 13; ++nt) {
      bool ok = (nt*16 + c) < SEQ;
      #pragma unroll
      for (int r = 0; r < 4; ++r) {
        float v = ok ? sc[nt][r] * 0.125f : -1e30f;
        sc[nt][r] = v;
        mx[r] = fmaxf(mx[r], v);
      }
    }
    #pragma unroll
    for (int r = 0; r < 4; ++r) {
      #pragma unroll
      for (int o = 1; o < 16; o <<= 1) mx[r] = fmaxf(mx[r], __shfl_xor(mx[r], o));
      sm[r] = 0.f;
    }
    #pragma unroll
    for (int nt = 0; nt < 13; ++nt) {
      #pragma unroll
      for (int r = 0; r < 4; ++r) { float p = __expf(sc[nt][r] - mx[r]); sc[nt][r] = p; sm[r] += p; }
    }
    #pragma unroll
    for (int r = 0; r < 4; ++r) {
      #pragma unroll
      for (int o = 1; o < 16; o <<= 1) sm[r] += __shfl_xor(sm[r], o);
      sm[r] = 1.f / sm[r];
    }
    #pragma unroll
    for (int nt = 0; nt < 13; ++nt) {
      #pragma unroll
      for (int r = 0; r < 4; ++r) {
        float p = sc[nt][r] * sm[r];
        unsigned short ph = f2bf(p);
        PbH[w][(quad*4 + r)*224 + nt*16 + c] = ph;
        PbL[w][(quad*4 + r)*224 + nt*16 + c] = f2bf(p - bf2f(ph));
      }
    }
    #pragma unroll
    for (int n2 = 0; n2 < 4; ++n2) {
      floatx4 o4 = {0.f,0.f,0.f,0.f};
      const unsigned short* vh = vHb + (long long)(n2*16 + c)*VPAD;
      const unsigned short* vl = vLb + (long long)(n2*16 + c)*VPAD;
      #pragma unroll
      for (int ks = 0; ks < 7; ++ks) {
        short8 ph = *(const short8*)&PbH[w][c*224 + ks*32 + quad*8];
        short8 pl = *(const short8*)&PbL[w][c*224 + ks*32 + quad*8];
        short8 bvh = *(const short8*)(vh + ks*32 + quad*8);
        short8 bvl = *(const short8*)(vl + ks*32 + quad*8);
        o4 = __builtin_amdgcn_mfma_f32_16x16x32_bf16(ph, bvh, o4, 0, 0, 0);
        o4 = __builtin_amdgcn_mfma_f32_16x16x32_bf16(ph, bvl, o4, 0, 0, 0);
        o4 = __builtin_amdgcn_mfma_f32_16x16x32_bf16(pl, bvh, o4, 0, 0, 0);
      }
      #pragma unroll
      for (int r = 0; r < 4; ++r) {
        int qg = q0 + quad*4 + r;
        if (qg < SEQ) {
          long long oi = (long long)(qg*BAT + b)*DM + h*64 + n2*16 + c;
          float v = o4[r];
          unsigned short hh = f2bf(v);
          oHi[oi] = hh;
          oLo[oi] = f2bf(v - bf2f(hh));
        }
      }
    }
  }
}

// ---------------- host ----------------

extern "C" void kernel_launch(void* const* d_in, const int* in_sizes, int n_in,
                              void* d_out, int out_size, void* d_ws, size_t ws_size,
                              hipStream_t stream) {
  const float* in_x    = (const float*)d_in[0];
  const float* p_mln1s = (const float*)d_in[1];
  const float* p_mln1b = (const float*)d_in[2];
  const float* p_minw  = (const float*)d_in[3];
  const float* p_minb  = (const float*)d_in[4];
  const float* p_moutw = (const float*)d_in[5];
  const float* p_moutb = (const float*)d_in[6];
  const float* p_mln2s = (const float*)d_in[7];
  const float* p_mln2b = (const float*)d_in[8];
  const float* p_gate  = (const float*)d_in[9];
  const float* p_w1    = (const float*)d_in[10];
  const float* p_b1    = (const float*)d_in[11];
  const float* p_w2    = (const float*)d_in[12];
  const float* p_b2    = (const float*)d_in[13];
  const float* p_sln1s = (const float*)d_in[14];
  const float* p_sln1b = (const float*)d_in[15];
  const float* p_sinw  = (const float*)d_in[16];
  const float* p_sinb  = (const float*)d_in[17];
  const float* p_soutw = (const float*)d_in[18];
  const float* p_soutb = (const float*)d_in[19];
  const float* p_sln2s = (const float*)d_in[20];
  const float* p_sln2b = (const float*)d_in[21];
  const float* p_sfcw  = (const float*)d_in[22];
  const float* p_sfcb  = (const float*)d_in[23];
  const float* p_sprojw= (const float*)d_in[24];
  const float* p_sprojb= (const float*)d_in[25];

  float* xout   = (float*)d_out;
  float* logits = xout + (long long)TOK * DM;

  char* wp = (char*)d_ws;
  auto carve = [&](long long bytes) -> char* {
    char* r = wp; wp += (bytes + 255) & ~255LL; return r;
  };
  unsigned short* lnB   = (unsigned short*)carve((long long)TOK * DM * 2);
  unsigned short* lnLo  = (unsigned short*)carve((long long)TOK * DM * 2);
  unsigned short* bigB  = (unsigned short*)carve((long long)SLOTS * FF * 2);  // qkvHi | Hbuf
  unsigned short* attnB = (unsigned short*)carve((long long)TOK * DM * 2);
  unsigned short* attnLo= (unsigned short*)carve((long long)TOK * DM * 2);
  float*          Ybuf  = (float*)carve((long long)SLOTS * DM * 4);           // aliases qkvLo
  unsigned short* vThi  = (unsigned short*)carve((long long)BAT*NH*64*VPAD*2 + 64);
  unsigned short* vTlo  = (unsigned short*)carve((long long)BAT*NH*64*VPAD*2 + 64);
  unsigned short* wreg  = (unsigned short*)carve(40108032LL * 2);
  unsigned short* wInLo = (unsigned short*)carve((long long)D3*DM*2);
  unsigned short* wOutLo= (unsigned short*)carve((long long)DM*DM*2);
  int*   counts   = (int*)carve(64);
  int*   cur      = (int*)carve(64);
  int*   tileCnt  = (int*)carve(64);
  int4*  tileMap  = (int4*)carve(256 * 16);
  int*   e0 = (int*)carve(TOK*4); int* e1 = (int*)carve(TOK*4);
  float* w0 = (float*)carve(TOK*4); float* w1 = (float*)carve(TOK*4);
  int*   perm  = (int*)carve(SLOTS*4);
  float* wslot = (float*)carve(SLOTS*4);
  int*   slotA = (int*)carve(TOK*4); int* slotB = (int*)carve(TOK*4);
  (void)in_sizes; (void)n_in; (void)out_size; (void)ws_size;

  unsigned short* qkvB  = bigB;
  unsigned short* qkvLo = (unsigned short*)Ybuf;
  unsigned short* Hbuf  = bigB;
  unsigned short* wIn  = wreg;
  unsigned short* wOut = wreg + 1769472;
  unsigned short* wFc1 = wreg + 2359296;
  unsigned short* wFc2 = wreg + 21233664;

  copy_k<<<4096, 256, 0, stream>>>(xout, in_x, (long long)TOK*DM/4);

  for (int layer = 0; layer < 4; ++layer) {
    bool moe = layer < 2;
    bool hp  = (layer == 0);
    int li = moe ? layer : layer - 2;
    const float* ln1s = moe ? p_mln1s + li*DM : p_sln1s + li*DM;
    const float* ln1b = moe ? p_mln1b + li*DM : p_sln1b + li*DM;
    const float* inw  = moe ? p_minw + (long long)li*D3*DM : p_sinw + (long long)li*D3*DM;
    const float* inb  = moe ? p_minb + li*D3 : p_sinb + li*D3;
    const float* outw = moe ? p_moutw + (long long)li*DM*DM : p_soutw + (long long)li*DM*DM;
    const float* outb = moe ? p_moutb + li*DM : p_soutb + li*DM;
    const float* ln2s = moe ? p_mln2s + li*DM : p_sln2s + li*DM;
    const float* ln2b = moe ? p_mln2b + li*DM : p_sln2b + li*DM;

    if (hp) {
      conv2_k<<<2048, 256, 0, stream>>>(wIn, wInLo, inw, (long long)D3*DM/4);
      conv2_k<<<1024, 256, 0, stream>>>(wOut, wOutLo, outw, (long long)DM*DM/4);
    } else {
      conv_k<<<2048, 256, 0, stream>>>(wIn,  inw,  (long long)D3*DM/4);
      conv_k<<<1024, 256, 0, stream>>>(wOut, outw, (long long)DM*DM/4);
    }
    if (moe) {
      conv_k<<<4096, 256, 0, stream>>>(wFc1, p_w1 + (long long)li*NE*FF*DM, (long long)NE*FF*DM/4);
      conv_k<<<4096, 256, 0, stream>>>(wFc2, p_w2 + (long long)li*NE*DM*FF, (long long)NE*DM*FF/4);
    } else {
      conv_k<<<2048, 256, 0, stream>>>(wFc1, p_sfcw   + (long long)li*FF*DM, (long long)FF*DM/4);
      conv_k<<<2048, 256, 0, stream>>>(wFc2, p_sprojw + (long long)li*DM*FF, (long long)DM*FF/4);
    }

    if (hp) {
      ln2bf_k<<<TOK/4, 256, 0, stream>>>(xout, ln1s, ln1b, lnB, lnLo);
      gemm_hp_k<0><<<dim3(D3/128, 99), 256, 0, stream>>>(lnB, lnLo, wIn, wInLo, inb,
          TOK, D3, DM, qkvB, qkvLo, nullptr);
      vtrans_k<<<BAT*NH, 256, 0, stream>>>(qkvB, qkvLo, vThi, vTlo);
      attn_hp_k<<<BAT*NH, 256, 0, stream>>>(qkvB, qkvLo, vThi, vTlo, attnB, attnLo);
      gemm_hp_k<1><<<dim3(DM/128, 99), 256, 0, stream>>>(attnB, attnLo, wOut, wOutLo, outb,
          TOK, DM, DM, nullptr, nullptr, xout);
    } else {
      ln_k<<<TOK/4, 256, 0, stream>>>(xout, ln1s, ln1b, lnB);
      gemm_k<0,false,false><<<dim3(D3/128, 99), 256, 0, stream>>>(lnB, wIn, inb, TOK, D3, DM,
          nullptr, nullptr, nullptr, nullptr, qkvB, nullptr, 0, 0);
      attn_k<<<BAT*NH, 256, 0, stream>>>(qkvB, attnB);
      gemm_k<2,false,false><<<dim3(DM/128, 99), 256, 0, stream>>>(attnB, wOut, outb, TOK, DM, DM,
          nullptr, nullptr, nullptr, nullptr, nullptr, xout, 0, 0);
    }
    ln_k<<<TOK/4, 256, 0, stream>>>(xout, ln2s, ln2b, lnB);

    if (layer == 0) {
      zero_k<<<1, 64, 0, stream>>>(counts, 8);
      gate_k<<<TOK/4, 256, 0, stream>>>(xout, ln2s, ln2b, p_gate, logits, e0, e1, w0, w1);
      hist_k<<<64, 256, 0, stream>>>(e0, e1, counts);
      tilemap_k<<<1, 1, 0, stream>>>(counts, cur, tileMap, tileCnt);
      scatter_k<<<(TOK+255)/256, 256, 0, stream>>>(e0, e1, w0, w1, cur, perm, wslot, slotA, slotB);
    }

    if (moe) {
      gemm_k<1,true,true><<<dim3(FF/128, 205), 256, 0, stream>>>(lnB, wFc1, p_b1 + (long long)li*NE*FF,
          SLOTS, FF, DM, perm, tileMap, tileCnt, nullptr, Hbuf, nullptr, (long long)FF*DM, FF);
      gemm_k<3,true,false><<<dim3(DM/128, 205), 256, 0, stream>>>(Hbuf, wFc2, p_b2 + (long long)li*NE*DM,
          SLOTS, DM, FF, nullptr, tileMap, tileCnt, wslot, nullptr, Ybuf, (long long)DM*FF, DM);
      combine_k<<<TOK*(DM/4)/256, 256, 0, stream>>>(xout, Ybuf, slotA, slotB);
    } else {
      gemm_k<1,false,false><<<dim3(FF/128, 99), 256, 0, stream>>>(lnB, wFc1, p_sfcb + li*FF,
          TOK, FF, DM, nullptr, nullptr, nullptr, nullptr, Hbuf, nullptr, 0, 0);
      gemm_k<2,false,false><<<dim3(DM/128, 99), 256, 0, stream>>>(Hbuf, wFc2, p_sprojb + li*DM,
          TOK, DM, FF, nullptr, nullptr, nullptr, nullptr, nullptr, xout, 0, 0);
    }
  }
}

// Round 5
// 2993.293 us; speedup vs baseline: 1.1420x; 1.0443x over previous
//
#include <hip/hip_runtime.h>

#define TOK   12608
#define SLOTS 25216
#define DM    768
#define D3    2304
#define FF    3072
#define NH    12
#define SEQ   197
#define BAT   64
#define NE    8
#define VPAD  224

typedef short  short8  __attribute__((ext_vector_type(8)));
typedef float  floatx4 __attribute__((ext_vector_type(4)));

__device__ __forceinline__ unsigned short f2bf(float f) {
  union { float f; unsigned u; } c; c.f = f;
  unsigned r = c.u + 0x7fffu + ((c.u >> 16) & 1u);
  return (unsigned short)(r >> 16);
}
__device__ __forceinline__ float bf2f(unsigned short h) {
  union { unsigned u; float f; } c; c.u = ((unsigned)h) << 16; return c.f;
}

__device__ __forceinline__ void gl2lds16(const void* g, void* l) {
  __builtin_amdgcn_global_load_lds((const __attribute__((address_space(1))) unsigned int*)g,
                                   (__attribute__((address_space(3))) unsigned int*)l, 16, 0, 0);
}

// ---------------- elementwise ----------------

__global__ __launch_bounds__(256) void copy_k(float* __restrict__ dst, const float* __restrict__ src, long long n4) {
  long long i = (long long)blockIdx.x * 256 + threadIdx.x;
  long long st = (long long)gridDim.x * 256;
  for (; i < n4; i += st) ((floatx4*)dst)[i] = ((const floatx4*)src)[i];
}

__global__ __launch_bounds__(256) void conv_k(unsigned short* __restrict__ dst, const float* __restrict__ src, long long n4) {
  long long i = (long long)blockIdx.x * 256 + threadIdx.x;
  long long st = (long long)gridDim.x * 256;
  for (; i < n4; i += st) {
    floatx4 v = ((const floatx4*)src)[i];
    union { unsigned short u[4]; unsigned long long ll; } o;
    o.u[0] = f2bf(v.x); o.u[1] = f2bf(v.y); o.u[2] = f2bf(v.z); o.u[3] = f2bf(v.w);
    ((unsigned long long*)dst)[i] = o.ll;
  }
}

// hi/lo split cast
__global__ __launch_bounds__(256) void conv2_k(unsigned short* __restrict__ dhi, unsigned short* __restrict__ dlo,
                                               const float* __restrict__ src, long long n4) {
  long long i = (long long)blockIdx.x * 256 + threadIdx.x;
  long long st = (long long)gridDim.x * 256;
  for (; i < n4; i += st) {
    floatx4 v = ((const floatx4*)src)[i];
    union { unsigned short u[4]; unsigned long long ll; } oh, ol;
    #pragma unroll
    for (int j = 0; j < 4; ++j) {
      unsigned short h = f2bf(v[j]);
      oh.u[j] = h; ol.u[j] = f2bf(v[j] - bf2f(h));
    }
    ((unsigned long long*)dhi)[i] = oh.ll;
    ((unsigned long long*)dlo)[i] = ol.ll;
  }
}

__global__ void zero_k(int* p, int n) { int i = threadIdx.x; if (i < n) p[i] = 0; }

// wave-per-token layernorm -> bf16
__global__ __launch_bounds__(256) void ln_k(const float* __restrict__ x, const float* __restrict__ s,
                                            const float* __restrict__ b, unsigned short* __restrict__ out) {
  int t = blockIdx.x * 4 + (threadIdx.x >> 6);
  int lane = threadIdx.x & 63;
  const float* xr = x + (long long)t * DM;
  float v[12]; float s1 = 0.f, s2 = 0.f;
  #pragma unroll
  for (int i = 0; i < 12; ++i) { v[i] = xr[lane + i*64]; s1 += v[i]; s2 += v[i]*v[i]; }
  #pragma unroll
  for (int o = 1; o < 64; o <<= 1) { s1 += __shfl_xor(s1, o); s2 += __shfl_xor(s2, o); }
  float mu = s1 * (1.f/768.f);
  float inv = 1.f / sqrtf(s2*(1.f/768.f) - mu*mu + 1e-5f);
  unsigned short* orow = out + (long long)t * DM;
  #pragma unroll
  for (int i = 0; i < 12; ++i) { int f = lane + i*64; orow[f] = f2bf((v[i]-mu)*inv*s[f] + b[f]); }
}

// layernorm -> hi/lo bf16
__global__ __launch_bounds__(256) void ln2bf_k(const float* __restrict__ x, const float* __restrict__ s,
                                               const float* __restrict__ b, unsigned short* __restrict__ ohi,
                                               unsigned short* __restrict__ olo) {
  int t = blockIdx.x * 4 + (threadIdx.x >> 6);
  int lane = threadIdx.x & 63;
  const float* xr = x + (long long)t * DM;
  float v[12]; float s1 = 0.f, s2 = 0.f;
  #pragma unroll
  for (int i = 0; i < 12; ++i) { v[i] = xr[lane + i*64]; s1 += v[i]; s2 += v[i]*v[i]; }
  #pragma unroll
  for (int o = 1; o < 64; o <<= 1) { s1 += __shfl_xor(s1, o); s2 += __shfl_xor(s2, o); }
  float mu = s1 * (1.f/768.f);
  float inv = 1.f / sqrtf(s2*(1.f/768.f) - mu*mu + 1e-5f);
  unsigned short* rh = ohi + (long long)t * DM;
  unsigned short* rl = olo + (long long)t * DM;
  #pragma unroll
  for (int i = 0; i < 12; ++i) {
    int f = lane + i*64;
    float y = (v[i]-mu)*inv*s[f] + b[f];
    unsigned short h = f2bf(y);
    rh[f] = h; rl[f] = f2bf(y - bf2f(h));
  }
}

// fp32 LN + gating (no atomics)
__global__ __launch_bounds__(256) void gate_k(const float* __restrict__ x, const float* __restrict__ s,
    const float* __restrict__ b, const float* __restrict__ gw, float* __restrict__ logitsOut,
    int* __restrict__ e0, int* __restrict__ e1, float* __restrict__ w0, float* __restrict__ w1) {
  int t = blockIdx.x * 4 + (threadIdx.x >> 6);
  int lane = threadIdx.x & 63;
  const float* xr = x + (long long)t * DM;
  float v[12]; float s1 = 0.f, s2 = 0.f;
  #pragma unroll
  for (int i = 0; i < 12; ++i) { v[i] = xr[lane + i*64]; s1 += v[i]; s2 += v[i]*v[i]; }
  #pragma unroll
  for (int o = 1; o < 64; o <<= 1) { s1 += __shfl_xor(s1, o); s2 += __shfl_xor(s2, o); }
  float mu = s1 * (1.f/768.f);
  float inv = 1.f / sqrtf(s2*(1.f/768.f) - mu*mu + 1e-5f);
  float lg[8];
  #pragma unroll
  for (int e = 0; e < 8; ++e) lg[e] = 0.f;
  #pragma unroll
  for (int i = 0; i < 12; ++i) {
    int f = lane + i*64;
    float y = (v[i]-mu)*inv*s[f] + b[f];
    #pragma unroll
    for (int e = 0; e < 8; ++e) lg[e] += y * gw[e*DM + f];
  }
  #pragma unroll
  for (int e = 0; e < 8; ++e) {
    #pragma unroll
    for (int o = 1; o < 64; o <<= 1) lg[e] += __shfl_xor(lg[e], o);
  }
  if (lane == 0) {
    int a0 = 0;
    #pragma unroll
    for (int e = 1; e < 8; ++e) if (lg[e] > lg[a0]) a0 = e;
    int a1 = (a0 == 0) ? 1 : 0;
    #pragma unroll
    for (int e = 0; e < 8; ++e) if (e != a0 && lg[e] > lg[a1]) a1 = e;
    float mx = lg[a0];
    float pa = __expf(lg[a0]-mx), pb = __expf(lg[a1]-mx), iw = 1.f/(pa+pb);
    e0[t] = a0; e1[t] = a1; w0[t] = pa*iw; w1[t] = pb*iw;
    #pragma unroll
    for (int e = 0; e < 8; ++e) logitsOut[(long long)t*8 + e] = lg[e];
  }
}

// expert histogram
__global__ __launch_bounds__(256) void hist_k(const int* __restrict__ e0, const int* __restrict__ e1,
                                              int* __restrict__ counts) {
  __shared__ int hc[8];
  int tid = threadIdx.x;
  if (tid < 8) hc[tid] = 0;
  __syncthreads();
  int c[8];
  #pragma unroll
  for (int e = 0; e < 8; ++e) c[e] = 0;
  for (int t = blockIdx.x * 256 + tid; t < TOK; t += gridDim.x * 256) {
    int a = e0[t], b = e1[t];
    #pragma unroll
    for (int e = 0; e < 8; ++e) c[e] += (a == e) + (b == e);
  }
  #pragma unroll
  for (int e = 0; e < 8; ++e) {
    #pragma unroll
    for (int o = 1; o < 64; o <<= 1) c[e] += __shfl_xor(c[e], o);
  }
  if ((tid & 63) == 0) {
    #pragma unroll
    for (int e = 0; e < 8; ++e) atomicAdd(&hc[e], c[e]);
  }
  __syncthreads();
  if (tid < 8 && hc[tid]) atomicAdd(&counts[tid], hc[tid]);
}

__global__ void tilemap_k(const int* __restrict__ counts, int* __restrict__ cur,
                          int4* __restrict__ tileMap, int* __restrict__ tileCount) {
  if (threadIdx.x == 0 && blockIdx.x == 0) {
    int off = 0, nt = 0;
    for (int e = 0; e < 8; ++e) {
      cur[e] = off;
      int cnt = counts[e];
      for (int s = 0; s < cnt; s += 128) {
        int rows = cnt - s; if (rows > 128) rows = 128;
        tileMap[nt++] = make_int4(e, off + s, rows, 0);
      }
      off += cnt;
    }
    *tileCount = nt;
  }
}

// wave-aggregated fetch-add scatter
__global__ __launch_bounds__(256) void scatter_k(const int* __restrict__ e0, const int* __restrict__ e1,
    const float* __restrict__ w0, const float* __restrict__ w1, int* __restrict__ cur,
    int* __restrict__ perm, float* __restrict__ wslot, int* __restrict__ slotA, int* __restrict__ slotB) {
  int t = blockIdx.x * 256 + threadIdx.x;
  int lane = threadIdx.x & 63;
  bool valid = t < TOK;
  int a = valid ? e0[t] : -1;
  int b = valid ? e1[t] : -1;
  int sa = 0, sb = 0;
  #pragma unroll
  for (int e = 0; e < 8; ++e) {
    unsigned long long m = __ballot(a == e);
    int cnt = (int)__popcll(m);
    int base = 0;
    if (lane == 0 && cnt) base = atomicAdd(&cur[e], cnt);
    base = __shfl(base, 0);
    if (a == e) sa = base + (int)__popcll(m & ((1ull << lane) - 1ull));

    unsigned long long m2 = __ballot(b == e);
    int cnt2 = (int)__popcll(m2);
    int base2 = 0;
    if (lane == 0 && cnt2) base2 = atomicAdd(&cur[e], cnt2);
    base2 = __shfl(base2, 0);
    if (b == e) sb = base2 + (int)__popcll(m2 & ((1ull << lane) - 1ull));
  }
  if (valid) {
    perm[sa] = t; wslot[sa] = w0[t]; slotA[t] = sa;
    perm[sb] = t; wslot[sb] = w1[t]; slotB[t] = sb;
  }
}

__global__ __launch_bounds__(256) void combine_k(float* __restrict__ x, const float* __restrict__ Y,
    const int* __restrict__ sA, const int* __restrict__ sB) {
  int idx = blockIdx.x * 256 + threadIdx.x;
  int t = idx / (DM/4), f = idx % (DM/4);
  const floatx4* ya = (const floatx4*)(Y + (long long)sA[t]*DM);
  const floatx4* yb = (const floatx4*)(Y + (long long)sB[t]*DM);
  floatx4* xp = (floatx4*)(x + (long long)t*DM);
  xp[f] = xp[f] + ya[f] + yb[f];
}

// V transpose (hp layer 0)
__global__ __launch_bounds__(256) void vtrans_k(const unsigned short* __restrict__ hi,
    const unsigned short* __restrict__ lo, unsigned short* __restrict__ vThi,
    unsigned short* __restrict__ vTlo) {
  __shared__ unsigned short tH[64][65], tL[64][65];
  int bh = blockIdx.x; int b = bh / NH, h = bh % NH;
  int t = threadIdx.x; int d = t & 63, sl = t >> 6;
  for (int chunk = 0; chunk < 4; ++chunk) {
    __syncthreads();
    #pragma unroll
    for (int r = 0; r < 16; ++r) {
      int sp = r*4 + sl;
      int sg = chunk*64 + sp;
      unsigned short vh = 0, vl = 0;
      if (sg < SEQ) {
        long long off = (long long)(sg*BAT + b)*D3 + 2*DM + h*64 + d;
        vh = hi[off]; vl = lo[off];
      }
      tH[sp][d] = vh; tL[sp][d] = vl;
    }
    __syncthreads();
    int s2 = t & 63, dd0 = t >> 6;
    if (chunk*64 + s2 < VPAD) {
      #pragma unroll
      for (int r = 0; r < 16; ++r) {
        int dd = r*4 + dd0;
        long long oi = ((long long)bh*64 + dd)*VPAD + chunk*64 + s2;
        vThi[oi] = tH[s2][dd];
        vTlo[oi] = tL[s2][dd];
      }
    }
  }
}

// ---------------- 128x128 bf16 MFMA GEMM, BK=64 (two K-panels, one barrier pair per 64-K) ----
template<int MODE, bool GATHER, bool PERM>
__global__ __launch_bounds__(256) void gemm_k(
    const unsigned short* __restrict__ A, const unsigned short* __restrict__ Bw,
    const float* __restrict__ bias, int M, int N, int K,
    const int* __restrict__ perm, const int4* __restrict__ tileMap,
    const int* __restrict__ tileCount, const float* __restrict__ wslot,
    unsigned short* __restrict__ outB, float* __restrict__ outF,
    long long bStrideE, int biasStrideE) {
  int e = 0, rowStart, rows;
  if (GATHER) {
    if ((int)blockIdx.y >= *tileCount) return;
    int4 tm = tileMap[blockIdx.y];
    e = tm.x; rowStart = tm.y; rows = tm.z;
  } else {
    rowStart = blockIdx.y * 128;
    rows = M - rowStart; if (rows > 128) rows = 128;
  }
  __shared__ __align__(16) unsigned short As[2][128*32];
  __shared__ __align__(16) unsigned short Bs[2][128*32];
  int tid = threadIdx.x, lane = tid & 63, w = tid >> 6;
  int n0 = blockIdx.x * 128;
  const unsigned short* Bp = Bw + (long long)e * bStrideE;
  const float* biasp = bias + (long long)e * biasStrideE;

  const char* aSrc[2]; const char* bSrc[2];
  unsigned short* ldsA[2][2]; unsigned short* ldsB[2][2];
  #pragma unroll
  for (int j = 0; j < 2; ++j) {
    int row = j*64 + w*16 + (lane >> 2);
    int kb  = (lane & 3) * 16;
    int ar  = row < rows ? row : rows - 1;
    long long srcRow;
    if (GATHER) { int slot = rowStart + ar; srcRow = PERM ? (long long)perm[slot] : (long long)slot; }
    else        srcRow = rowStart + ar;
    aSrc[j] = (const char*)(A + srcRow * (long long)K) + kb;
    bSrc[j] = (const char*)(Bp + (long long)(n0 + row) * K) + kb;
    #pragma unroll
    for (int p = 0; p < 2; ++p) {
      ldsA[p][j] = &As[p][j*2048 + w*512];
      ldsB[p][j] = &Bs[p][j*2048 + w*512];
    }
  }

  floatx4 acc[4][4];
  floatx4 zf = {0.f, 0.f, 0.f, 0.f};
  #pragma unroll
  for (int i = 0; i < 4; ++i)
    #pragma unroll
    for (int j = 0; j < 4; ++j) acc[i][j] = zf;

  int wm = w >> 1, wn = w & 1;
  int aOff = (wm*64 + (lane & 15))*32 + (lane >> 4)*8;
  int bOff = (wn*64 + (lane & 15))*32 + (lane >> 4)*8;

  for (int k0 = 0; k0 < K; k0 += 64) {
    long long kb2 = (long long)k0 * 2;
    #pragma unroll
    for (int p = 0; p < 2; ++p)
      #pragma unroll
      for (int j = 0; j < 2; ++j) {
        gl2lds16(aSrc[j] + kb2 + p*64, ldsA[p][j]);
        gl2lds16(bSrc[j] + kb2 + p*64, ldsB[p][j]);
      }
    __syncthreads();
    #pragma unroll
    for (int p = 0; p < 2; ++p) {
      short8 aF[4], bF[4];
      #pragma unroll
      for (int i = 0; i < 4; ++i) aF[i] = *(const short8*)&As[p][aOff + i*512];
      #pragma unroll
      for (int j = 0; j < 4; ++j) bF[j] = *(const short8*)&Bs[p][bOff + j*512];
      #pragma unroll
      for (int i = 0; i < 4; ++i)
        #pragma unroll
        for (int j = 0; j < 4; ++j)
          acc[i][j] = __builtin_amdgcn_mfma_f32_16x16x32_bf16(aF[i], bF[j], acc[i][j], 0, 0, 0);
    }
    __syncthreads();
  }

  int quad = lane >> 4, c = lane & 15;
  #pragma unroll
  for (int i = 0; i < 4; ++i) {
    int rl0 = wm*64 + i*16 + quad*4;
    #pragma unroll
    for (int j = 0; j < 4; ++j) {
      int col = n0 + wn*64 + j*16 + c;
      float bc = biasp[col];
      #pragma unroll
      for (int r = 0; r < 4; ++r) {
        int rl = rl0 + r;
        if (rl < rows) {
          long long orow = (long long)(rowStart + rl);
          float v = acc[i][j][r] + bc;
          if (MODE == 0) {
            outB[orow*N + col] = f2bf(v);
          } else if (MODE == 1) {
            float g = v * __builtin_amdgcn_rcpf(1.f + __expf(-1.702f * v));
            outB[orow*N + col] = f2bf(g);
          } else if (MODE == 2) {
            outF[orow*N + col] += v;
          } else {
            outF[orow*N + col] = wslot[orow] * v;
          }
        }
      }
    }
  }
}

// ---------------- split-precision (hi/lo bf16, 3-product) GEMM, BK=32 ----------------
template<int HPMODE>
__global__ __launch_bounds__(256) void gemm_hp_k(
    const unsigned short* __restrict__ Ahi, const unsigned short* __restrict__ Alo,
    const unsigned short* __restrict__ Bhi, const unsigned short* __restrict__ Blo,
    const float* __restrict__ bias, int M, int N, int K,
    unsigned short* __restrict__ oHi, unsigned short* __restrict__ oLo,
    float* __restrict__ outF) {
  int rowStart = blockIdx.y * 128;
  int rows = M - rowStart; if (rows > 128) rows = 128;
  __shared__ __align__(16) unsigned short AsH[128*32];
  __shared__ __align__(16) unsigned short AsL[128*32];
  __shared__ __align__(16) unsigned short BsH[128*32];
  __shared__ __align__(16) unsigned short BsL[128*32];
  int tid = threadIdx.x, lane = tid & 63, w = tid >> 6;
  int n0 = blockIdx.x * 128;

  const char *aH[2], *aL[2], *bH[2], *bL[2];
  unsigned short *lAH[2], *lAL[2], *lBH[2], *lBL[2];
  #pragma unroll
  for (int j = 0; j < 2; ++j) {
    int row = j*64 + w*16 + (lane >> 2);
    int kb  = (lane & 3) * 16;
    int ar  = row < rows ? row : rows - 1;
    long long srcRow = rowStart + ar;
    aH[j] = (const char*)(Ahi + srcRow * (long long)K) + kb;
    aL[j] = (const char*)(Alo + srcRow * (long long)K) + kb;
    bH[j] = (const char*)(Bhi + (long long)(n0 + row) * K) + kb;
    bL[j] = (const char*)(Blo + (long long)(n0 + row) * K) + kb;
    lAH[j] = &AsH[j*2048 + w*512]; lAL[j] = &AsL[j*2048 + w*512];
    lBH[j] = &BsH[j*2048 + w*512]; lBL[j] = &BsL[j*2048 + w*512];
  }

  floatx4 acc[4][4];
  floatx4 zf = {0.f, 0.f, 0.f, 0.f};
  #pragma unroll
  for (int i = 0; i < 4; ++i)
    #pragma unroll
    for (int j = 0; j < 4; ++j) acc[i][j] = zf;

  int wm = w >> 1, wn = w & 1;
  int aOff = (wm*64 + (lane & 15))*32 + (lane >> 4)*8;
  int bOff = (wn*64 + (lane & 15))*32 + (lane >> 4)*8;

  for (int k0 = 0; k0 < K; k0 += 32) {
    long long kb2 = (long long)k0 * 2;
    #pragma unroll
    for (int j = 0; j < 2; ++j) {
      gl2lds16(aH[j] + kb2, lAH[j]);
      gl2lds16(aL[j] + kb2, lAL[j]);
      gl2lds16(bH[j] + kb2, lBH[j]);
      gl2lds16(bL[j] + kb2, lBL[j]);
    }
    __syncthreads();
    short8 ah[4], al[4], bh[4], bl[4];
    #pragma unroll
    for (int i = 0; i < 4; ++i) {
      ah[i] = *(const short8*)&AsH[aOff + i*512];
      al[i] = *(const short8*)&AsL[aOff + i*512];
    }
    #pragma unroll
    for (int j = 0; j < 4; ++j) {
      bh[j] = *(const short8*)&BsH[bOff + j*512];
      bl[j] = *(const short8*)&BsL[bOff + j*512];
    }
    #pragma unroll
    for (int i = 0; i < 4; ++i)
      #pragma unroll
      for (int j = 0; j < 4; ++j) {
        acc[i][j] = __builtin_amdgcn_mfma_f32_16x16x32_bf16(ah[i], bh[j], acc[i][j], 0, 0, 0);
        acc[i][j] = __builtin_amdgcn_mfma_f32_16x16x32_bf16(ah[i], bl[j], acc[i][j], 0, 0, 0);
        acc[i][j] = __builtin_amdgcn_mfma_f32_16x16x32_bf16(al[i], bh[j], acc[i][j], 0, 0, 0);
      }
    __syncthreads();
  }

  int quad = lane >> 4, c = lane & 15;
  #pragma unroll
  for (int i = 0; i < 4; ++i) {
    int rl0 = wm*64 + i*16 + quad*4;
    #pragma unroll
    for (int j = 0; j < 4; ++j) {
      int col = n0 + wn*64 + j*16 + c;
      float bc = bias[col];
      #pragma unroll
      for (int r = 0; r < 4; ++r) {
        int rl = rl0 + r;
        if (rl < rows) {
          long long orow = (long long)(rowStart + rl);
          float v = acc[i][j][r] + bc;
          if (HPMODE == 0) {
            unsigned short h = f2bf(v);
            oHi[orow*N + col] = h;
            oLo[orow*N + col] = f2bf(v - bf2f(h));
          } else {
            outF[orow*N + col] += v;
          }
        }
      }
    }
  }
}

// ---------------- attention (standard bf16): one block per (b,h) ----------------
__global__ __launch_bounds__(256) void attn_k(const unsigned short* __restrict__ qkv,
                                              unsigned short* __restrict__ out) {
  __shared__ __align__(16) unsigned short Vt[64*224];
  __shared__ __align__(16) unsigned short Pb[4][16*224];
  int bh = blockIdx.x; int b = bh / NH, h = bh % NH;
  int tid = threadIdx.x, lane = tid & 63, w = tid >> 6;
  for (int idx = tid; idx < 224*64; idx += 256) {
    int key = idx >> 6, d = idx & 63;
    unsigned short v = 0;
    if (key < SEQ) v = qkv[(long long)(key*BAT + b)*D3 + 2*DM + h*64 + d];
    Vt[d*224 + key] = v;
  }
  for (int idx = tid; idx < 4*16*224; idx += 256) ((unsigned short*)Pb)[idx] = 0;
  __syncthreads();

  int quad = lane >> 4, c = lane & 15;
  for (int qt = w; qt < 13; qt += 4) {
    int q0 = qt * 16;
    int qrow = q0 + c; int sq = qrow < SEQ ? qrow : SEQ-1;
    const unsigned short* qp = qkv + (long long)(sq*BAT + b)*D3 + h*64 + quad*8;
    short8 aq0 = *(const short8*)qp;
    short8 aq1 = *(const short8*)(qp + 32);
    floatx4 sc[13];
    #pragma unroll
    for (int nt = 0; nt < 13; ++nt) {
      int key = nt*16 + c; int sk = key < SEQ ? key : SEQ-1;
      const unsigned short* kp = qkv + (long long)(sk*BAT + b)*D3 + DM + h*64 + quad*8;
      short8 bk0 = *(const short8*)kp;
      short8 bk1 = *(const short8*)(kp + 32);
      floatx4 z = {0.f,0.f,0.f,0.f};
      z = __builtin_amdgcn_mfma_f32_16x16x32_bf16(aq0, bk0, z, 0, 0, 0);
      z = __builtin_amdgcn_mfma_f32_16x16x32_bf16(aq1, bk1, z, 0, 0, 0);
      sc[nt] = z;
    }
    float mx[4], sm[4];
    #pragma unroll
    for (int r = 0; r < 4; ++r) mx[r] = -1e30f;
    #pragma unroll
    for (int nt = 0; nt < 13; ++nt) {
      bool ok = (nt*16 + c) < SEQ;
      #pragma unroll
      for (int r = 0; r < 4; ++r) {
        float v = ok ? sc[nt][r] * 0.125f : -1e30f;
        sc[nt][r] = v;
        mx[r] = fmaxf(mx[r], v);
      }
    }
    #pragma unroll
    for (int r = 0; r < 4; ++r) {
      #pragma unroll
      for (int o = 1; o < 16; o <<= 1) mx[r] = fmaxf(mx[r], __shfl_xor(mx[r], o));
      sm[r] = 0.f;
    }
    #pragma unroll
    for (int nt = 0; nt < 13; ++nt) {
      #pragma unroll
      for (int r = 0; r < 4; ++r) { float p = __expf(sc[nt][r] - mx[r]); sc[nt][r] = p; sm[r] += p; }
    }
    #pragma unroll
    for (int r = 0; r < 4; ++r) {
      #pragma unroll
      for (int o = 1; o < 16; o <<= 1) sm[r] += __shfl_xor(sm[r], o);
      sm[r] = 1.f / sm[r];
    }
    #pragma unroll
    for (int nt = 0; nt < 13; ++nt) {
      #pragma unroll
      for (int r = 0; r < 4; ++r)
        Pb[w][(quad*4 + r)*224 + nt*16 + c] = f2bf(sc[nt][r] * sm[r]);
    }
    #pragma unroll
    for (int n2 = 0; n2 < 4; ++n2) {
      floatx4 o4 = {0.f,0.f,0.f,0.f};
      #pragma unroll
      for (int ks = 0; ks < 7; ++ks) {
        short8 ap = *(const short8*)&Pb[w][c*224 + ks*32 + quad*8];
        short8 bv = *(const short8*)&Vt[(n2*16 + c)*224 + ks*32 + quad*8];
        o4 = __builtin_amdgcn_mfma_f32_16x16x32_bf16(ap, bv, o4, 0, 0, 0);
      }
      #pragma unroll
      for (int r = 0; r < 4; ++r) {
        int qg = q0 + quad*4 + r;
        if (qg < SEQ)
          out[(long long)(qg*BAT + b)*DM + h*64 + n2*16 + c] = f2bf(o4[r]);
      }
    }
  }
}

// ---------------- attention, split precision 3-product (layer 0) ----------------
__global__ __launch_bounds__(256) void attn_hp_k(
    const unsigned short* __restrict__ qh, const unsigned short* __restrict__ ql,
    const unsigned short* __restrict__ vThi, const unsigned short* __restrict__ vTlo,
    unsigned short* __restrict__ oHi, unsigned short* __restrict__ oLo) {
  __shared__ __align__(16) unsigned short PbH[4][16*224];
  __shared__ __align__(16) unsigned short PbL[4][16*224];
  int bh = blockIdx.x; int b = bh / NH, h = bh % NH;
  int tid = threadIdx.x, lane = tid & 63, w = tid >> 6;
  for (int idx = lane; idx < 16*224; idx += 64) { PbH[w][idx] = 0; PbL[w][idx] = 0; }

  int quad = lane >> 4, c = lane & 15;
  const unsigned short* vHb = vThi + (long long)bh * 64 * VPAD;
  const unsigned short* vLb = vTlo + (long long)bh * 64 * VPAD;

  for (int qt = w; qt < 13; qt += 4) {
    int q0 = qt * 16;
    int qrow = q0 + c; int sq = qrow < SEQ ? qrow : SEQ-1;
    long long qoff = (long long)(sq*BAT + b)*D3 + h*64 + quad*8;
    short8 qh0 = *(const short8*)(qh + qoff);
    short8 qh1 = *(const short8*)(qh + qoff + 32);
    short8 ql0 = *(const short8*)(ql + qoff);
    short8 ql1 = *(const short8*)(ql + qoff + 32);
    floatx4 sc[13];
    #pragma unroll
    for (int nt = 0; nt < 13; ++nt) {
      int key = nt*16 + c; int sk = key < SEQ ? key : SEQ-1;
      long long koff = (long long)(sk*BAT + b)*D3 + DM + h*64 + quad*8;
      short8 kh0 = *(const short8*)(qh + koff);
      short8 kh1 = *(const short8*)(qh + koff + 32);
      short8 kl0 = *(const short8*)(ql + koff);
      short8 kl1 = *(const short8*)(ql + koff + 32);
      floatx4 z = {0.f,0.f,0.f,0.f};
      z = __builtin_amdgcn_mfma_f32_16x16x32_bf16(qh0, kh0, z, 0, 0, 0);
      z = __builtin_amdgcn_mfma_f32_16x16x32_bf16(qh0, kl0, z, 0, 0, 0);
      z = __builtin_amdgcn_mfma_f32_16x16x32_bf16(ql0, kh0, z, 0, 0, 0);
      z = __builtin_amdgcn_mfma_f32_16x16x32_bf16(qh1, kh1, z, 0, 0, 0);
      z = __builtin_amdgcn_mfma_f32_16x16x32_bf16(qh1, kl1, z, 0, 0, 0);
      z = __builtin_amdgcn_mfma_f32_16x16x32_bf16(ql1, kh1, z, 0, 0, 0);
      sc[nt] = z;
    }
    float mx[4], sm[4];
    #pragma unroll
    for (int r = 0; r < 4; ++r) mx[r] = -1e30f;
    #pragma unroll
    for (int nt = 0; nt < 13; ++nt) {
      bool ok = (nt*16 + c) < SEQ;
      #pragma unroll
      for (int r = 0; r < 4; ++r) {
        float v = ok ? sc[nt][r] * 0.125f : -1e30f;
        sc[nt][r] = v;
        mx[r] = fmaxf(mx[r], v);
      }
    }
    #pragma unroll
    for (int r = 0; r < 4; ++r) {
      #pragma unroll
      for (int o = 1; o < 16; o <<= 1) mx[r] = fmaxf(mx[r], __shfl_xor(mx[r], o));
      sm[r] = 0.f;
    }
    #pragma unroll
    for (int nt = 0; nt < 13; ++nt) {
      #pragma unroll
      for (int r = 0; r < 4; ++r) { float p = __expf(sc[nt][r] - mx[r]); sc[nt][r] = p; sm[r] += p; }
    }
    #pragma unroll
    for (int r = 0; r < 4; ++r) {
      #pragma unroll
      for (int o = 1; o < 16; o <<= 1) sm[r] += __shfl_xor(sm[r], o);
      sm[r] = 1.f / sm[r];
    }
    #pragma unroll
    for (int nt = 0; nt < 13; ++nt) {
      #pragma unroll
      for (int r = 0; r < 4; ++r) {
        float p = sc[nt][r] * sm[r];
        unsigned short ph = f2bf(p);
        PbH[w][(quad*4 + r)*224 + nt*16 + c] = ph;
        PbL[w][(quad*4 + r)*224 + nt*16 + c] = f2bf(p - bf2f(ph));
      }
    }
    #pragma unroll
    for (int n2 = 0; n2 < 4; ++n2) {
      floatx4 o4 = {0.f,0.f,0.f,0.f};
      const unsigned short* vh = vHb + (long long)(n2*16 + c)*VPAD;
      const unsigned short* vl = vLb + (long long)(n2*16 + c)*VPAD;
      #pragma unroll
      for (int ks = 0; ks < 7; ++ks) {
        short8 ph = *(const short8*)&PbH[w][c*224 + ks*32 + quad*8];
        short8 pl = *(const short8*)&PbL[w][c*224 + ks*32 + quad*8];
        short8 bvh = *(const short8*)(vh + ks*32 + quad*8);
        short8 bvl = *(const short8*)(vl + ks*32 + quad*8);
        o4 = __builtin_amdgcn_mfma_f32_16x16x32_bf16(ph, bvh, o4, 0, 0, 0);
        o4 = __builtin_amdgcn_mfma_f32_16x16x32_bf16(ph, bvl, o4, 0, 0, 0);
        o4 = __builtin_amdgcn_mfma_f32_16x16x32_bf16(pl, bvh, o4, 0, 0, 0);
      }
      #pragma unroll
      for (int r = 0; r < 4; ++r) {
        int qg = q0 + quad*4 + r;
        if (qg < SEQ) {
          long long oi = (long long)(qg*BAT + b)*DM + h*64 + n2*16 + c;
          float v = o4[r];
          unsigned short hh = f2bf(v);
          oHi[oi] = hh;
          oLo[oi] = f2bf(v - bf2f(hh));
        }
      }
    }
  }
}

// ---------------- host ----------------

extern "C" void kernel_launch(void* const* d_in, const int* in_sizes, int n_in,
                              void* d_out, int out_size, void* d_ws, size_t ws_size,
                              hipStream_t stream) {
  const float* in_x    = (const float*)d_in[0];
  const float* p_mln1s = (const float*)d_in[1];
  const float* p_mln1b = (const float*)d_in[2];
  const float* p_minw  = (const float*)d_in[3];
  const float* p_minb  = (const float*)d_in[4];
  const float* p_moutw = (const float*)d_in[5];
  const float* p_moutb = (const float*)d_in[6];
  const float* p_mln2s = (const float*)d_in[7];
  const float* p_mln2b = (const float*)d_in[8];
  const float* p_gate  = (const float*)d_in[9];
  const float* p_w1    = (const float*)d_in[10];
  const float* p_b1    = (const float*)d_in[11];
  const float* p_w2    = (const float*)d_in[12];
  const float* p_b2    = (const float*)d_in[13];
  const float* p_sln1s = (const float*)d_in[14];
  const float* p_sln1b = (const float*)d_in[15];
  const float* p_sinw  = (const float*)d_in[16];
  const float* p_sinb  = (const float*)d_in[17];
  const float* p_soutw = (const float*)d_in[18];
  const float* p_soutb = (const float*)d_in[19];
  const float* p_sln2s = (const float*)d_in[20];
  const float* p_sln2b = (const float*)d_in[21];
  const float* p_sfcw  = (const float*)d_in[22];
  const float* p_sfcb  = (const float*)d_in[23];
  const float* p_sprojw= (const float*)d_in[24];
  const float* p_sprojb= (const float*)d_in[25];

  float* xout   = (float*)d_out;
  float* logits = xout + (long long)TOK * DM;

  char* wp = (char*)d_ws;
  auto carve = [&](long long bytes) -> char* {
    char* r = wp; wp += (bytes + 255) & ~255LL; return r;
  };
  unsigned short* lnB   = (unsigned short*)carve((long long)TOK * DM * 2);
  unsigned short* lnLo  = (unsigned short*)carve((long long)TOK * DM * 2);
  unsigned short* bigB  = (unsigned short*)carve((long long)SLOTS * FF * 2);  // qkvHi | Hbuf
  unsigned short* attnB = (unsigned short*)carve((long long)TOK * DM * 2);
  unsigned short* attnLo= (unsigned short*)carve((long long)TOK * DM * 2);
  float*          Ybuf  = (float*)carve((long long)SLOTS * DM * 4);           // aliases qkvLo
  unsigned short* vThi  = (unsigned short*)carve((long long)BAT*NH*64*VPAD*2 + 64);
  unsigned short* vTlo  = (unsigned short*)carve((long long)BAT*NH*64*VPAD*2 + 64);
  unsigned short* wreg  = (unsigned short*)carve(40108032LL * 2);
  unsigned short* wInLo = (unsigned short*)carve((long long)D3*DM*2);
  unsigned short* wOutLo= (unsigned short*)carve((long long)DM*DM*2);
  int*   counts   = (int*)carve(64);
  int*   cur      = (int*)carve(64);
  int*   tileCnt  = (int*)carve(64);
  int4*  tileMap  = (int4*)carve(256 * 16);
  int*   e0 = (int*)carve(TOK*4); int* e1 = (int*)carve(TOK*4);
  float* w0 = (float*)carve(TOK*4); float* w1 = (float*)carve(TOK*4);
  int*   perm  = (int*)carve(SLOTS*4);
  float* wslot = (float*)carve(SLOTS*4);
  int*   slotA = (int*)carve(TOK*4); int* slotB = (int*)carve(TOK*4);
  (void)in_sizes; (void)n_in; (void)out_size; (void)ws_size;

  unsigned short* qkvB  = bigB;
  unsigned short* qkvLo = (unsigned short*)Ybuf;
  unsigned short* Hbuf  = bigB;
  unsigned short* wIn  = wreg;
  unsigned short* wOut = wreg + 1769472;
  unsigned short* wFc1 = wreg + 2359296;
  unsigned short* wFc2 = wreg + 21233664;

  copy_k<<<4096, 256, 0, stream>>>(xout, in_x, (long long)TOK*DM/4);

  for (int layer = 0; layer < 4; ++layer) {
    bool moe = layer < 2;
    bool hp  = (layer == 0);
    int li = moe ? layer : layer - 2;
    const float* ln1s = moe ? p_mln1s + li*DM : p_sln1s + li*DM;
    const float* ln1b = moe ? p_mln1b + li*DM : p_sln1b + li*DM;
    const float* inw  = moe ? p_minw + (long long)li*D3*DM : p_sinw + (long long)li*D3*DM;
    const float* inb  = moe ? p_minb + li*D3 : p_sinb + li*D3;
    const float* outw = moe ? p_moutw + (long long)li*DM*DM : p_soutw + (long long)li*DM*DM;
    const float* outb = moe ? p_moutb + li*DM : p_soutb + li*DM;
    const float* ln2s = moe ? p_mln2s + li*DM : p_sln2s + li*DM;
    const float* ln2b = moe ? p_mln2b + li*DM : p_sln2b + li*DM;

    if (hp) {
      conv2_k<<<2048, 256, 0, stream>>>(wIn, wInLo, inw, (long long)D3*DM/4);
      conv2_k<<<1024, 256, 0, stream>>>(wOut, wOutLo, outw, (long long)DM*DM/4);
    } else {
      conv_k<<<2048, 256, 0, stream>>>(wIn,  inw,  (long long)D3*DM/4);
      conv_k<<<1024, 256, 0, stream>>>(wOut, outw, (long long)DM*DM/4);
    }
    if (moe) {
      conv_k<<<4096, 256, 0, stream>>>(wFc1, p_w1 + (long long)li*NE*FF*DM, (long long)NE*FF*DM/4);
      conv_k<<<4096, 256, 0, stream>>>(wFc2, p_w2 + (long long)li*NE*DM*FF, (long long)NE*DM*FF/4);
    } else {
      conv_k<<<2048, 256, 0, stream>>>(wFc1, p_sfcw   + (long long)li*FF*DM, (long long)FF*DM/4);
      conv_k<<<2048, 256, 0, stream>>>(wFc2, p_sprojw + (long long)li*DM*FF, (long long)DM*FF/4);
    }

    if (hp) {
      ln2bf_k<<<TOK/4, 256, 0, stream>>>(xout, ln1s, ln1b, lnB, lnLo);
      gemm_hp_k<0><<<dim3(D3/128, 99), 256, 0, stream>>>(lnB, lnLo, wIn, wInLo, inb,
          TOK, D3, DM, qkvB, qkvLo, nullptr);
      vtrans_k<<<BAT*NH, 256, 0, stream>>>(qkvB, qkvLo, vThi, vTlo);
      attn_hp_k<<<BAT*NH, 256, 0, stream>>>(qkvB, qkvLo, vThi, vTlo, attnB, attnLo);
      gemm_hp_k<1><<<dim3(DM/128, 99), 256, 0, stream>>>(attnB, attnLo, wOut, wOutLo, outb,
          TOK, DM, DM, nullptr, nullptr, xout);
    } else {
      ln_k<<<TOK/4, 256, 0, stream>>>(xout, ln1s, ln1b, lnB);
      gemm_k<0,false,false><<<dim3(D3/128, 99), 256, 0, stream>>>(lnB, wIn, inb, TOK, D3, DM,
          nullptr, nullptr, nullptr, nullptr, qkvB, nullptr, 0, 0);
      attn_k<<<BAT*NH, 256, 0, stream>>>(qkvB, attnB);
      gemm_k<2,false,false><<<dim3(DM/128, 99), 256, 0, stream>>>(attnB, wOut, outb, TOK, DM, DM,
          nullptr, nullptr, nullptr, nullptr, nullptr, xout, 0, 0);
    }
    ln_k<<<TOK/4, 256, 0, stream>>>(xout, ln2s, ln2b, lnB);

    if (layer == 0) {
      zero_k<<<1, 64, 0, stream>>>(counts, 8);
      gate_k<<<TOK/4, 256, 0, stream>>>(xout, ln2s, ln2b, p_gate, logits, e0, e1, w0, w1);
      hist_k<<<64, 256, 0, stream>>>(e0, e1, counts);
      tilemap_k<<<1, 1, 0, stream>>>(counts, cur, tileMap, tileCnt);
      scatter_k<<<(TOK+255)/256, 256, 0, stream>>>(e0, e1, w0, w1, cur, perm, wslot, slotA, slotB);
    }

    if (moe) {
      gemm_k<1,true,true><<<dim3(FF/128, 205), 256, 0, stream>>>(lnB, wFc1, p_b1 + (long long)li*NE*FF,
          SLOTS, FF, DM, perm, tileMap, tileCnt, nullptr, Hbuf, nullptr, (long long)FF*DM, FF);
      gemm_k<3,true,false><<<dim3(DM/128, 205), 256, 0, stream>>>(Hbuf, wFc2, p_b2 + (long long)li*NE*DM,
          SLOTS, DM, FF, nullptr, tileMap, tileCnt, wslot, nullptr, Ybuf, (long long)DM*FF, DM);
      combine_k<<<TOK*(DM/4)/256, 256, 0, stream>>>(xout, Ybuf, slotA, slotB);
    } else {
      gemm_k<1,false,false><<<dim3(FF/128, 99), 256, 0, stream>>>(lnB, wFc1, p_sfcb + li*FF,
          TOK, FF, DM, nullptr, nullptr, nullptr, nullptr, Hbuf, nullptr, 0, 0);
      gemm_k<2,false,false><<<dim3(DM/128, 99), 256, 0, stream>>>(Hbuf, wFc2, p_sprojb + li*DM,
          TOK, DM, FF, nullptr, nullptr, nullptr, nullptr, nullptr, xout, 0, 0);
    }
  }
}

// Round 6
// 2920.940 us; speedup vs baseline: 1.1703x; 1.0248x over previous
//
#include <hip/hip_runtime.h>

#define TOK   12608
#define SLOTS 25216
#define DM    768
#define D3    2304
#define FF    3072
#define NH    12
#define SEQ   197
#define BAT   64
#define NE    8
#define VPAD  224

typedef short  short8  __attribute__((ext_vector_type(8)));
typedef float  floatx4 __attribute__((ext_vector_type(4)));

__device__ __forceinline__ unsigned short f2bf(float f) {
  union { float f; unsigned u; } c; c.f = f;
  unsigned r = c.u + 0x7fffu + ((c.u >> 16) & 1u);
  return (unsigned short)(r >> 16);
}
__device__ __forceinline__ float bf2f(unsigned short h) {
  union { unsigned u; float f; } c; c.u = ((unsigned)h) << 16; return c.f;
}

__device__ __forceinline__ void gl2lds16(const void* g, void* l) {
  __builtin_amdgcn_global_load_lds((const __attribute__((address_space(1))) unsigned int*)g,
                                   (__attribute__((address_space(3))) unsigned int*)l, 16, 0, 0);
}

// bijective XCD-chunked block remap (m204): each XCD gets a contiguous work range,
// so all N-blocks sharing an A-panel land on one XCD's L2.
__device__ __forceinline__ void xcd_remap(int& bx, int& by) {
  int gx = gridDim.x;
  int nwg = gx * gridDim.y;
  int bid = blockIdx.y * gx + blockIdx.x;
  int q = nwg >> 3, r = nwg & 7;
  int xcd = bid & 7, idx = bid >> 3;
  int wg = (xcd < r ? xcd * (q + 1) : r * (q + 1) + (xcd - r) * q) + idx;
  bx = wg % gx; by = wg / gx;
}

// ---------------- elementwise ----------------

__global__ __launch_bounds__(256) void copy_k(float* __restrict__ dst, const float* __restrict__ src, long long n4) {
  long long i = (long long)blockIdx.x * 256 + threadIdx.x;
  long long st = (long long)gridDim.x * 256;
  for (; i < n4; i += st) ((floatx4*)dst)[i] = ((const floatx4*)src)[i];
}

__global__ __launch_bounds__(256) void conv_k(unsigned short* __restrict__ dst, const float* __restrict__ src, long long n4) {
  long long i = (long long)blockIdx.x * 256 + threadIdx.x;
  long long st = (long long)gridDim.x * 256;
  for (; i < n4; i += st) {
    floatx4 v = ((const floatx4*)src)[i];
    union { unsigned short u[4]; unsigned long long ll; } o;
    o.u[0] = f2bf(v.x); o.u[1] = f2bf(v.y); o.u[2] = f2bf(v.z); o.u[3] = f2bf(v.w);
    ((unsigned long long*)dst)[i] = o.ll;
  }
}

// hi/lo split cast
__global__ __launch_bounds__(256) void conv2_k(unsigned short* __restrict__ dhi, unsigned short* __restrict__ dlo,
                                               const float* __restrict__ src, long long n4) {
  long long i = (long long)blockIdx.x * 256 + threadIdx.x;
  long long st = (long long)gridDim.x * 256;
  for (; i < n4; i += st) {
    floatx4 v = ((const floatx4*)src)[i];
    union { unsigned short u[4]; unsigned long long ll; } oh, ol;
    #pragma unroll
    for (int j = 0; j < 4; ++j) {
      unsigned short h = f2bf(v[j]);
      oh.u[j] = h; ol.u[j] = f2bf(v[j] - bf2f(h));
    }
    ((unsigned long long*)dhi)[i] = oh.ll;
    ((unsigned long long*)dlo)[i] = ol.ll;
  }
}

__global__ void zero_k(int* p, int n) { int i = threadIdx.x; if (i < n) p[i] = 0; }

// wave-per-token layernorm -> bf16
__global__ __launch_bounds__(256) void ln_k(const float* __restrict__ x, const float* __restrict__ s,
                                            const float* __restrict__ b, unsigned short* __restrict__ out) {
  int t = blockIdx.x * 4 + (threadIdx.x >> 6);
  int lane = threadIdx.x & 63;
  const float* xr = x + (long long)t * DM;
  float v[12]; float s1 = 0.f, s2 = 0.f;
  #pragma unroll
  for (int i = 0; i < 12; ++i) { v[i] = xr[lane + i*64]; s1 += v[i]; s2 += v[i]*v[i]; }
  #pragma unroll
  for (int o = 1; o < 64; o <<= 1) { s1 += __shfl_xor(s1, o); s2 += __shfl_xor(s2, o); }
  float mu = s1 * (1.f/768.f);
  float inv = 1.f / sqrtf(s2*(1.f/768.f) - mu*mu + 1e-5f);
  unsigned short* orow = out + (long long)t * DM;
  #pragma unroll
  for (int i = 0; i < 12; ++i) { int f = lane + i*64; orow[f] = f2bf((v[i]-mu)*inv*s[f] + b[f]); }
}

// layernorm -> hi/lo bf16
__global__ __launch_bounds__(256) void ln2bf_k(const float* __restrict__ x, const float* __restrict__ s,
                                               const float* __restrict__ b, unsigned short* __restrict__ ohi,
                                               unsigned short* __restrict__ olo) {
  int t = blockIdx.x * 4 + (threadIdx.x >> 6);
  int lane = threadIdx.x & 63;
  const float* xr = x + (long long)t * DM;
  float v[12]; float s1 = 0.f, s2 = 0.f;
  #pragma unroll
  for (int i = 0; i < 12; ++i) { v[i] = xr[lane + i*64]; s1 += v[i]; s2 += v[i]*v[i]; }
  #pragma unroll
  for (int o = 1; o < 64; o <<= 1) { s1 += __shfl_xor(s1, o); s2 += __shfl_xor(s2, o); }
  float mu = s1 * (1.f/768.f);
  float inv = 1.f / sqrtf(s2*(1.f/768.f) - mu*mu + 1e-5f);
  unsigned short* rh = ohi + (long long)t * DM;
  unsigned short* rl = olo + (long long)t * DM;
  #pragma unroll
  for (int i = 0; i < 12; ++i) {
    int f = lane + i*64;
    float y = (v[i]-mu)*inv*s[f] + b[f];
    unsigned short h = f2bf(y);
    rh[f] = h; rl[f] = f2bf(y - bf2f(h));
  }
}

// fp32 LN + gating (no atomics)
__global__ __launch_bounds__(256) void gate_k(const float* __restrict__ x, const float* __restrict__ s,
    const float* __restrict__ b, const float* __restrict__ gw, float* __restrict__ logitsOut,
    int* __restrict__ e0, int* __restrict__ e1, float* __restrict__ w0, float* __restrict__ w1) {
  int t = blockIdx.x * 4 + (threadIdx.x >> 6);
  int lane = threadIdx.x & 63;
  const float* xr = x + (long long)t * DM;
  float v[12]; float s1 = 0.f, s2 = 0.f;
  #pragma unroll
  for (int i = 0; i < 12; ++i) { v[i] = xr[lane + i*64]; s1 += v[i]; s2 += v[i]*v[i]; }
  #pragma unroll
  for (int o = 1; o < 64; o <<= 1) { s1 += __shfl_xor(s1, o); s2 += __shfl_xor(s2, o); }
  float mu = s1 * (1.f/768.f);
  float inv = 1.f / sqrtf(s2*(1.f/768.f) - mu*mu + 1e-5f);
  float lg[8];
  #pragma unroll
  for (int e = 0; e < 8; ++e) lg[e] = 0.f;
  #pragma unroll
  for (int i = 0; i < 12; ++i) {
    int f = lane + i*64;
    float y = (v[i]-mu)*inv*s[f] + b[f];
    #pragma unroll
    for (int e = 0; e < 8; ++e) lg[e] += y * gw[e*DM + f];
  }
  #pragma unroll
  for (int e = 0; e < 8; ++e) {
    #pragma unroll
    for (int o = 1; o < 64; o <<= 1) lg[e] += __shfl_xor(lg[e], o);
  }
  if (lane == 0) {
    int a0 = 0;
    #pragma unroll
    for (int e = 1; e < 8; ++e) if (lg[e] > lg[a0]) a0 = e;
    int a1 = (a0 == 0) ? 1 : 0;
    #pragma unroll
    for (int e = 0; e < 8; ++e) if (e != a0 && lg[e] > lg[a1]) a1 = e;
    float mx = lg[a0];
    float pa = __expf(lg[a0]-mx), pb = __expf(lg[a1]-mx), iw = 1.f/(pa+pb);
    e0[t] = a0; e1[t] = a1; w0[t] = pa*iw; w1[t] = pb*iw;
    #pragma unroll
    for (int e = 0; e < 8; ++e) logitsOut[(long long)t*8 + e] = lg[e];
  }
}

// expert histogram
__global__ __launch_bounds__(256) void hist_k(const int* __restrict__ e0, const int* __restrict__ e1,
                                              int* __restrict__ counts) {
  __shared__ int hc[8];
  int tid = threadIdx.x;
  if (tid < 8) hc[tid] = 0;
  __syncthreads();
  int c[8];
  #pragma unroll
  for (int e = 0; e < 8; ++e) c[e] = 0;
  for (int t = blockIdx.x * 256 + tid; t < TOK; t += gridDim.x * 256) {
    int a = e0[t], b = e1[t];
    #pragma unroll
    for (int e = 0; e < 8; ++e) c[e] += (a == e) + (b == e);
  }
  #pragma unroll
  for (int e = 0; e < 8; ++e) {
    #pragma unroll
    for (int o = 1; o < 64; o <<= 1) c[e] += __shfl_xor(c[e], o);
  }
  if ((tid & 63) == 0) {
    #pragma unroll
    for (int e = 0; e < 8; ++e) atomicAdd(&hc[e], c[e]);
  }
  __syncthreads();
  if (tid < 8 && hc[tid]) atomicAdd(&counts[tid], hc[tid]);
}

__global__ void tilemap_k(const int* __restrict__ counts, int* __restrict__ cur,
                          int4* __restrict__ tileMap, int* __restrict__ tileCount) {
  if (threadIdx.x == 0 && blockIdx.x == 0) {
    int off = 0, nt = 0;
    for (int e = 0; e < 8; ++e) {
      cur[e] = off;
      int cnt = counts[e];
      for (int s = 0; s < cnt; s += 128) {
        int rows = cnt - s; if (rows > 128) rows = 128;
        tileMap[nt++] = make_int4(e, off + s, rows, 0);
      }
      off += cnt;
    }
    *tileCount = nt;
  }
}

// wave-aggregated fetch-add scatter
__global__ __launch_bounds__(256) void scatter_k(const int* __restrict__ e0, const int* __restrict__ e1,
    const float* __restrict__ w0, const float* __restrict__ w1, int* __restrict__ cur,
    int* __restrict__ perm, float* __restrict__ wslot, int* __restrict__ slotA, int* __restrict__ slotB) {
  int t = blockIdx.x * 256 + threadIdx.x;
  int lane = threadIdx.x & 63;
  bool valid = t < TOK;
  int a = valid ? e0[t] : -1;
  int b = valid ? e1[t] : -1;
  int sa = 0, sb = 0;
  #pragma unroll
  for (int e = 0; e < 8; ++e) {
    unsigned long long m = __ballot(a == e);
    int cnt = (int)__popcll(m);
    int base = 0;
    if (lane == 0 && cnt) base = atomicAdd(&cur[e], cnt);
    base = __shfl(base, 0);
    if (a == e) sa = base + (int)__popcll(m & ((1ull << lane) - 1ull));

    unsigned long long m2 = __ballot(b == e);
    int cnt2 = (int)__popcll(m2);
    int base2 = 0;
    if (lane == 0 && cnt2) base2 = atomicAdd(&cur[e], cnt2);
    base2 = __shfl(base2, 0);
    if (b == e) sb = base2 + (int)__popcll(m2 & ((1ull << lane) - 1ull));
  }
  if (valid) {
    perm[sa] = t; wslot[sa] = w0[t]; slotA[t] = sa;
    perm[sb] = t; wslot[sb] = w1[t]; slotB[t] = sb;
  }
}

__global__ __launch_bounds__(256) void combine_k(float* __restrict__ x, const float* __restrict__ Y,
    const int* __restrict__ sA, const int* __restrict__ sB) {
  int idx = blockIdx.x * 256 + threadIdx.x;
  int t = idx / (DM/4), f = idx % (DM/4);
  const floatx4* ya = (const floatx4*)(Y + (long long)sA[t]*DM);
  const floatx4* yb = (const floatx4*)(Y + (long long)sB[t]*DM);
  floatx4* xp = (floatx4*)(x + (long long)t*DM);
  xp[f] = xp[f] + ya[f] + yb[f];
}

// V transpose (hp layer 0)
__global__ __launch_bounds__(256) void vtrans_k(const unsigned short* __restrict__ hi,
    const unsigned short* __restrict__ lo, unsigned short* __restrict__ vThi,
    unsigned short* __restrict__ vTlo) {
  __shared__ unsigned short tH[64][65], tL[64][65];
  int bh = blockIdx.x; int b = bh / NH, h = bh % NH;
  int t = threadIdx.x; int d = t & 63, sl = t >> 6;
  for (int chunk = 0; chunk < 4; ++chunk) {
    __syncthreads();
    #pragma unroll
    for (int r = 0; r < 16; ++r) {
      int sp = r*4 + sl;
      int sg = chunk*64 + sp;
      unsigned short vh = 0, vl = 0;
      if (sg < SEQ) {
        long long off = (long long)(sg*BAT + b)*D3 + 2*DM + h*64 + d;
        vh = hi[off]; vl = lo[off];
      }
      tH[sp][d] = vh; tL[sp][d] = vl;
    }
    __syncthreads();
    int s2 = t & 63, dd0 = t >> 6;
    if (chunk*64 + s2 < VPAD) {
      #pragma unroll
      for (int r = 0; r < 16; ++r) {
        int dd = r*4 + dd0;
        long long oi = ((long long)bh*64 + dd)*VPAD + chunk*64 + s2;
        vThi[oi] = tH[s2][dd];
        vTlo[oi] = tL[s2][dd];
      }
    }
  }
}

// ---------------- 128x128 bf16 MFMA GEMM, BK=64, XCD-chunked block swizzle ----
template<int MODE, bool GATHER, bool PERM>
__global__ __launch_bounds__(256) void gemm_k(
    const unsigned short* __restrict__ A, const unsigned short* __restrict__ Bw,
    const float* __restrict__ bias, int M, int N, int K,
    const int* __restrict__ perm, const int4* __restrict__ tileMap,
    const int* __restrict__ tileCount, const float* __restrict__ wslot,
    unsigned short* __restrict__ outB, float* __restrict__ outF,
    long long bStrideE, int biasStrideE) {
  int bx, by;
  xcd_remap(bx, by);
  int e = 0, rowStart, rows;
  if (GATHER) {
    if (by >= *tileCount) return;
    int4 tm = tileMap[by];
    e = tm.x; rowStart = tm.y; rows = tm.z;
  } else {
    rowStart = by * 128;
    rows = M - rowStart; if (rows > 128) rows = 128;
  }
  __shared__ __align__(16) unsigned short As[2][128*32];
  __shared__ __align__(16) unsigned short Bs[2][128*32];
  int tid = threadIdx.x, lane = tid & 63, w = tid >> 6;
  int n0 = bx * 128;
  const unsigned short* Bp = Bw + (long long)e * bStrideE;
  const float* biasp = bias + (long long)e * biasStrideE;

  const char* aSrc[2]; const char* bSrc[2];
  unsigned short* ldsA[2][2]; unsigned short* ldsB[2][2];
  #pragma unroll
  for (int j = 0; j < 2; ++j) {
    int row = j*64 + w*16 + (lane >> 2);
    int kb  = (lane & 3) * 16;
    int ar  = row < rows ? row : rows - 1;
    long long srcRow;
    if (GATHER) { int slot = rowStart + ar; srcRow = PERM ? (long long)perm[slot] : (long long)slot; }
    else        srcRow = rowStart + ar;
    aSrc[j] = (const char*)(A + srcRow * (long long)K) + kb;
    bSrc[j] = (const char*)(Bp + (long long)(n0 + row) * K) + kb;
    #pragma unroll
    for (int p = 0; p < 2; ++p) {
      ldsA[p][j] = &As[p][j*2048 + w*512];
      ldsB[p][j] = &Bs[p][j*2048 + w*512];
    }
  }

  floatx4 acc[4][4];
  floatx4 zf = {0.f, 0.f, 0.f, 0.f};
  #pragma unroll
  for (int i = 0; i < 4; ++i)
    #pragma unroll
    for (int j = 0; j < 4; ++j) acc[i][j] = zf;

  int wm = w >> 1, wn = w & 1;
  int aOff = (wm*64 + (lane & 15))*32 + (lane >> 4)*8;
  int bOff = (wn*64 + (lane & 15))*32 + (lane >> 4)*8;

  for (int k0 = 0; k0 < K; k0 += 64) {
    long long kb2 = (long long)k0 * 2;
    #pragma unroll
    for (int p = 0; p < 2; ++p)
      #pragma unroll
      for (int j = 0; j < 2; ++j) {
        gl2lds16(aSrc[j] + kb2 + p*64, ldsA[p][j]);
        gl2lds16(bSrc[j] + kb2 + p*64, ldsB[p][j]);
      }
    __syncthreads();
    #pragma unroll
    for (int p = 0; p < 2; ++p) {
      short8 aF[4], bF[4];
      #pragma unroll
      for (int i = 0; i < 4; ++i) aF[i] = *(const short8*)&As[p][aOff + i*512];
      #pragma unroll
      for (int j = 0; j < 4; ++j) bF[j] = *(const short8*)&Bs[p][bOff + j*512];
      #pragma unroll
      for (int i = 0; i < 4; ++i)
        #pragma unroll
        for (int j = 0; j < 4; ++j)
          acc[i][j] = __builtin_amdgcn_mfma_f32_16x16x32_bf16(aF[i], bF[j], acc[i][j], 0, 0, 0);
    }
    __syncthreads();
  }

  int quad = lane >> 4, c = lane & 15;
  #pragma unroll
  for (int i = 0; i < 4; ++i) {
    int rl0 = wm*64 + i*16 + quad*4;
    #pragma unroll
    for (int j = 0; j < 4; ++j) {
      int col = n0 + wn*64 + j*16 + c;
      float bc = biasp[col];
      #pragma unroll
      for (int r = 0; r < 4; ++r) {
        int rl = rl0 + r;
        if (rl < rows) {
          long long orow = (long long)(rowStart + rl);
          float v = acc[i][j][r] + bc;
          if (MODE == 0) {
            outB[orow*N + col] = f2bf(v);
          } else if (MODE == 1) {
            float g = v * __builtin_amdgcn_rcpf(1.f + __expf(-1.702f * v));
            outB[orow*N + col] = f2bf(g);
          } else if (MODE == 2) {
            outF[orow*N + col] += v;
          } else {
            outF[orow*N + col] = wslot[orow] * v;
          }
        }
      }
    }
  }
}

// ---------------- split-precision (hi/lo bf16, 3-product) GEMM, BK=32 ----------------
template<int HPMODE>
__global__ __launch_bounds__(256) void gemm_hp_k(
    const unsigned short* __restrict__ Ahi, const unsigned short* __restrict__ Alo,
    const unsigned short* __restrict__ Bhi, const unsigned short* __restrict__ Blo,
    const float* __restrict__ bias, int M, int N, int K,
    unsigned short* __restrict__ oHi, unsigned short* __restrict__ oLo,
    float* __restrict__ outF) {
  int bx, by;
  xcd_remap(bx, by);
  int rowStart = by * 128;
  int rows = M - rowStart; if (rows > 128) rows = 128;
  __shared__ __align__(16) unsigned short AsH[128*32];
  __shared__ __align__(16) unsigned short AsL[128*32];
  __shared__ __align__(16) unsigned short BsH[128*32];
  __shared__ __align__(16) unsigned short BsL[128*32];
  int tid = threadIdx.x, lane = tid & 63, w = tid >> 6;
  int n0 = bx * 128;

  const char *aH[2], *aL[2], *bH[2], *bL[2];
  unsigned short *lAH[2], *lAL[2], *lBH[2], *lBL[2];
  #pragma unroll
  for (int j = 0; j < 2; ++j) {
    int row = j*64 + w*16 + (lane >> 2);
    int kb  = (lane & 3) * 16;
    int ar  = row < rows ? row : rows - 1;
    long long srcRow = rowStart + ar;
    aH[j] = (const char*)(Ahi + srcRow * (long long)K) + kb;
    aL[j] = (const char*)(Alo + srcRow * (long long)K) + kb;
    bH[j] = (const char*)(Bhi + (long long)(n0 + row) * K) + kb;
    bL[j] = (const char*)(Blo + (long long)(n0 + row) * K) + kb;
    lAH[j] = &AsH[j*2048 + w*512]; lAL[j] = &AsL[j*2048 + w*512];
    lBH[j] = &BsH[j*2048 + w*512]; lBL[j] = &BsL[j*2048 + w*512];
  }

  floatx4 acc[4][4];
  floatx4 zf = {0.f, 0.f, 0.f, 0.f};
  #pragma unroll
  for (int i = 0; i < 4; ++i)
    #pragma unroll
    for (int j = 0; j < 4; ++j) acc[i][j] = zf;

  int wm = w >> 1, wn = w & 1;
  int aOff = (wm*64 + (lane & 15))*32 + (lane >> 4)*8;
  int bOff = (wn*64 + (lane & 15))*32 + (lane >> 4)*8;

  for (int k0 = 0; k0 < K; k0 += 32) {
    long long kb2 = (long long)k0 * 2;
    #pragma unroll
    for (int j = 0; j < 2; ++j) {
      gl2lds16(aH[j] + kb2, lAH[j]);
      gl2lds16(aL[j] + kb2, lAL[j]);
      gl2lds16(bH[j] + kb2, lBH[j]);
      gl2lds16(bL[j] + kb2, lBL[j]);
    }
    __syncthreads();
    short8 ah[4], al[4], bh[4], bl[4];
    #pragma unroll
    for (int i = 0; i < 4; ++i) {
      ah[i] = *(const short8*)&AsH[aOff + i*512];
      al[i] = *(const short8*)&AsL[aOff + i*512];
    }
    #pragma unroll
    for (int j = 0; j < 4; ++j) {
      bh[j] = *(const short8*)&BsH[bOff + j*512];
      bl[j] = *(const short8*)&BsL[bOff + j*512];
    }
    #pragma unroll
    for (int i = 0; i < 4; ++i)
      #pragma unroll
      for (int j = 0; j < 4; ++j) {
        acc[i][j] = __builtin_amdgcn_mfma_f32_16x16x32_bf16(ah[i], bh[j], acc[i][j], 0, 0, 0);
        acc[i][j] = __builtin_amdgcn_mfma_f32_16x16x32_bf16(ah[i], bl[j], acc[i][j], 0, 0, 0);
        acc[i][j] = __builtin_amdgcn_mfma_f32_16x16x32_bf16(al[i], bh[j], acc[i][j], 0, 0, 0);
      }
    __syncthreads();
  }

  int quad = lane >> 4, c = lane & 15;
  #pragma unroll
  for (int i = 0; i < 4; ++i) {
    int rl0 = wm*64 + i*16 + quad*4;
    #pragma unroll
    for (int j = 0; j < 4; ++j) {
      int col = n0 + wn*64 + j*16 + c;
      float bc = bias[col];
      #pragma unroll
      for (int r = 0; r < 4; ++r) {
        int rl = rl0 + r;
        if (rl < rows) {
          long long orow = (long long)(rowStart + rl);
          float v = acc[i][j][r] + bc;
          if (HPMODE == 0) {
            unsigned short h = f2bf(v);
            oHi[orow*N + col] = h;
            oLo[orow*N + col] = f2bf(v - bf2f(h));
          } else {
            outF[orow*N + col] += v;
          }
        }
      }
    }
  }
}

// ---------------- attention (standard bf16): one block per (b,h) ----------------
__global__ __launch_bounds__(256) void attn_k(const unsigned short* __restrict__ qkv,
                                              unsigned short* __restrict__ out) {
  __shared__ __align__(16) unsigned short Vt[64*224];
  __shared__ __align__(16) unsigned short Pb[4][16*224];
  int bh = blockIdx.x; int b = bh / NH, h = bh % NH;
  int tid = threadIdx.x, lane = tid & 63, w = tid >> 6;
  for (int idx = tid; idx < 224*64; idx += 256) {
    int key = idx >> 6, d = idx & 63;
    unsigned short v = 0;
    if (key < SEQ) v = qkv[(long long)(key*BAT + b)*D3 + 2*DM + h*64 + d];
    Vt[d*224 + key] = v;
  }
  for (int idx = tid; idx < 4*16*224; idx += 256) ((unsigned short*)Pb)[idx] = 0;
  __syncthreads();

  int quad = lane >> 4, c = lane & 15;
  for (int qt = w; qt < 13; qt += 4) {
    int q0 = qt * 16;
    int qrow = q0 + c; int sq = qrow < SEQ ? qrow : SEQ-1;
    const unsigned short* qp = qkv + (long long)(sq*BAT + b)*D3 + h*64 + quad*8;
    short8 aq0 = *(const short8*)qp;
    short8 aq1 = *(const short8*)(qp + 32);
    floatx4 sc[13];
    #pragma unroll
    for (int nt = 0; nt < 13; ++nt) {
      int key = nt*16 + c; int sk = key < SEQ ? key : SEQ-1;
      const unsigned short* kp = qkv + (long long)(sk*BAT + b)*D3 + DM + h*64 + quad*8;
      short8 bk0 = *(const short8*)kp;
      short8 bk1 = *(const short8*)(kp + 32);
      floatx4 z = {0.f,0.f,0.f,0.f};
      z = __builtin_amdgcn_mfma_f32_16x16x32_bf16(aq0, bk0, z, 0, 0, 0);
      z = __builtin_amdgcn_mfma_f32_16x16x32_bf16(aq1, bk1, z, 0, 0, 0);
      sc[nt] = z;
    }
    float mx[4], sm[4];
    #pragma unroll
    for (int r = 0; r < 4; ++r) mx[r] = -1e30f;
    #pragma unroll
    for (int nt = 0; nt < 13; ++nt) {
      bool ok = (nt*16 + c) < SEQ;
      #pragma unroll
      for (int r = 0; r < 4; ++r) {
        float v = ok ? sc[nt][r] * 0.125f : -1e30f;
        sc[nt][r] = v;
        mx[r] = fmaxf(mx[r], v);
      }
    }
    #pragma unroll
    for (int r = 0; r < 4; ++r) {
      #pragma unroll
      for (int o = 1; o < 16; o <<= 1) mx[r] = fmaxf(mx[r], __shfl_xor(mx[r], o));
      sm[r] = 0.f;
    }
    #pragma unroll
    for (int nt = 0; nt < 13; ++nt) {
      #pragma unroll
      for (int r = 0; r < 4; ++r) { float p = __expf(sc[nt][r] - mx[r]); sc[nt][r] = p; sm[r] += p; }
    }
    #pragma unroll
    for (int r = 0; r < 4; ++r) {
      #pragma unroll
      for (int o = 1; o < 16; o <<= 1) sm[r] += __shfl_xor(sm[r], o);
      sm[r] = 1.f / sm[r];
    }
    #pragma unroll
    for (int nt = 0; nt < 13; ++nt) {
      #pragma unroll
      for (int r = 0; r < 4; ++r)
        Pb[w][(quad*4 + r)*224 + nt*16 + c] = f2bf(sc[nt][r] * sm[r]);
    }
    #pragma unroll
    for (int n2 = 0; n2 < 4; ++n2) {
      floatx4 o4 = {0.f,0.f,0.f,0.f};
      #pragma unroll
      for (int ks = 0; ks < 7; ++ks) {
        short8 ap = *(const short8*)&Pb[w][c*224 + ks*32 + quad*8];
        short8 bv = *(const short8*)&Vt[(n2*16 + c)*224 + ks*32 + quad*8];
        o4 = __builtin_amdgcn_mfma_f32_16x16x32_bf16(ap, bv, o4, 0, 0, 0);
      }
      #pragma unroll
      for (int r = 0; r < 4; ++r) {
        int qg = q0 + quad*4 + r;
        if (qg < SEQ)
          out[(long long)(qg*BAT + b)*DM + h*64 + n2*16 + c] = f2bf(o4[r]);
      }
    }
  }
}

// ---------------- attention, split precision 3-product (layer 0) ----------------
__global__ __launch_bounds__(256) void attn_hp_k(
    const unsigned short* __restrict__ qh, const unsigned short* __restrict__ ql,
    const unsigned short* __restrict__ vThi, const unsigned short* __restrict__ vTlo,
    unsigned short* __restrict__ oHi, unsigned short* __restrict__ oLo) {
  __shared__ __align__(16) unsigned short PbH[4][16*224];
  __shared__ __align__(16) unsigned short PbL[4][16*224];
  int bh = blockIdx.x; int b = bh / NH, h = bh % NH;
  int tid = threadIdx.x, lane = tid & 63, w = tid >> 6;
  for (int idx = lane; idx < 16*224; idx += 64) { PbH[w][idx] = 0; PbL[w][idx] = 0; }

  int quad = lane >> 4, c = lane & 15;
  const unsigned short* vHb = vThi + (long long)bh * 64 * VPAD;
  const unsigned short* vLb = vTlo + (long long)bh * 64 * VPAD;

  for (int qt = w; qt < 13; qt += 4) {
    int q0 = qt * 16;
    int qrow = q0 + c; int sq = qrow < SEQ ? qrow : SEQ-1;
    long long qoff = (long long)(sq*BAT + b)*D3 + h*64 + quad*8;
    short8 qh0 = *(const short8*)(qh + qoff);
    short8 qh1 = *(const short8*)(qh + qoff + 32);
    short8 ql0 = *(const short8*)(ql + qoff);
    short8 ql1 = *(const short8*)(ql + qoff + 32);
    floatx4 sc[13];
    #pragma unroll
    for (int nt = 0; nt < 13; ++nt) {
      int key = nt*16 + c; int sk = key < SEQ ? key : SEQ-1;
      long long koff = (long long)(sk*BAT + b)*D3 + DM + h*64 + quad*8;
      short8 kh0 = *(const short8*)(qh + koff);
      short8 kh1 = *(const short8*)(qh + koff + 32);
      short8 kl0 = *(const short8*)(ql + koff);
      short8 kl1 = *(const short8*)(ql + koff + 32);
      floatx4 z = {0.f,0.f,0.f,0.f};
      z = __builtin_amdgcn_mfma_f32_16x16x32_bf16(qh0, kh0, z, 0, 0, 0);
      z = __builtin_amdgcn_mfma_f32_16x16x32_bf16(qh0, kl0, z, 0, 0, 0);
      z = __builtin_amdgcn_mfma_f32_16x16x32_bf16(ql0, kh0, z, 0, 0, 0);
      z = __builtin_amdgcn_mfma_f32_16x16x32_bf16(qh1, kh1, z, 0, 0, 0);
      z = __builtin_amdgcn_mfma_f32_16x16x32_bf16(qh1, kl1, z, 0, 0, 0);
      z = __builtin_amdgcn_mfma_f32_16x16x32_bf16(ql1, kh1, z, 0, 0, 0);
      sc[nt] = z;
    }
    float mx[4], sm[4];
    #pragma unroll
    for (int r = 0; r < 4; ++r) mx[r] = -1e30f;
    #pragma unroll
    for (int nt = 0; nt < 13; ++nt) {
      bool ok = (nt*16 + c) < SEQ;
      #pragma unroll
      for (int r = 0; r < 4; ++r) {
        float v = ok ? sc[nt][r] * 0.125f : -1e30f;
        sc[nt][r] = v;
        mx[r] = fmaxf(mx[r], v);
      }
    }
    #pragma unroll
    for (int r = 0; r < 4; ++r) {
      #pragma unroll
      for (int o = 1; o < 16; o <<= 1) mx[r] = fmaxf(mx[r], __shfl_xor(mx[r], o));
      sm[r] = 0.f;
    }
    #pragma unroll
    for (int nt = 0; nt < 13; ++nt) {
      #pragma unroll
      for (int r = 0; r < 4; ++r) { float p = __expf(sc[nt][r] - mx[r]); sc[nt][r] = p; sm[r] += p; }
    }
    #pragma unroll
    for (int r = 0; r < 4; ++r) {
      #pragma unroll
      for (int o = 1; o < 16; o <<= 1) sm[r] += __shfl_xor(sm[r], o);
      sm[r] = 1.f / sm[r];
    }
    #pragma unroll
    for (int nt = 0; nt < 13; ++nt) {
      #pragma unroll
      for (int r = 0; r < 4; ++r) {
        float p = sc[nt][r] * sm[r];
        unsigned short ph = f2bf(p);
        PbH[w][(quad*4 + r)*224 + nt*16 + c] = ph;
        PbL[w][(quad*4 + r)*224 + nt*16 + c] = f2bf(p - bf2f(ph));
      }
    }
    #pragma unroll
    for (int n2 = 0; n2 < 4; ++n2) {
      floatx4 o4 = {0.f,0.f,0.f,0.f};
      const unsigned short* vh = vHb + (long long)(n2*16 + c)*VPAD;
      const unsigned short* vl = vLb + (long long)(n2*16 + c)*VPAD;
      #pragma unroll
      for (int ks = 0; ks < 7; ++ks) {
        short8 ph = *(const short8*)&PbH[w][c*224 + ks*32 + quad*8];
        short8 pl = *(const short8*)&PbL[w][c*224 + ks*32 + quad*8];
        short8 bvh = *(const short8*)(vh + ks*32 + quad*8);
        short8 bvl = *(const short8*)(vl + ks*32 + quad*8);
        o4 = __builtin_amdgcn_mfma_f32_16x16x32_bf16(ph, bvh, o4, 0, 0, 0);
        o4 = __builtin_amdgcn_mfma_f32_16x16x32_bf16(ph, bvl, o4, 0, 0, 0);
        o4 = __builtin_amdgcn_mfma_f32_16x16x32_bf16(pl, bvh, o4, 0, 0, 0);
      }
      #pragma unroll
      for (int r = 0; r < 4; ++r) {
        int qg = q0 + quad*4 + r;
        if (qg < SEQ) {
          long long oi = (long long)(qg*BAT + b)*DM + h*64 + n2*16 + c;
          float v = o4[r];
          unsigned short hh = f2bf(v);
          oHi[oi] = hh;
          oLo[oi] = f2bf(v - bf2f(hh));
        }
      }
    }
  }
}

// ---------------- host ----------------

extern "C" void kernel_launch(void* const* d_in, const int* in_sizes, int n_in,
                              void* d_out, int out_size, void* d_ws, size_t ws_size,
                              hipStream_t stream) {
  const float* in_x    = (const float*)d_in[0];
  const float* p_mln1s = (const float*)d_in[1];
  const float* p_mln1b = (const float*)d_in[2];
  const float* p_minw  = (const float*)d_in[3];
  const float* p_minb  = (const float*)d_in[4];
  const float* p_moutw = (const float*)d_in[5];
  const float* p_moutb = (const float*)d_in[6];
  const float* p_mln2s = (const float*)d_in[7];
  const float* p_mln2b = (const float*)d_in[8];
  const float* p_gate  = (const float*)d_in[9];
  const float* p_w1    = (const float*)d_in[10];
  const float* p_b1    = (const float*)d_in[11];
  const float* p_w2    = (const float*)d_in[12];
  const float* p_b2    = (const float*)d_in[13];
  const float* p_sln1s = (const float*)d_in[14];
  const float* p_sln1b = (const float*)d_in[15];
  const float* p_sinw  = (const float*)d_in[16];
  const float* p_sinb  = (const float*)d_in[17];
  const float* p_soutw = (const float*)d_in[18];
  const float* p_soutb = (const float*)d_in[19];
  const float* p_sln2s = (const float*)d_in[20];
  const float* p_sln2b = (const float*)d_in[21];
  const float* p_sfcw  = (const float*)d_in[22];
  const float* p_sfcb  = (const float*)d_in[23];
  const float* p_sprojw= (const float*)d_in[24];
  const float* p_sprojb= (const float*)d_in[25];

  float* xout   = (float*)d_out;
  float* logits = xout + (long long)TOK * DM;

  char* wp = (char*)d_ws;
  auto carve = [&](long long bytes) -> char* {
    char* r = wp; wp += (bytes + 255) & ~255LL; return r;
  };
  unsigned short* lnB   = (unsigned short*)carve((long long)TOK * DM * 2);
  unsigned short* lnLo  = (unsigned short*)carve((long long)TOK * DM * 2);
  unsigned short* bigB  = (unsigned short*)carve((long long)SLOTS * FF * 2);  // qkvHi | Hbuf
  unsigned short* attnB = (unsigned short*)carve((long long)TOK * DM * 2);
  unsigned short* attnLo= (unsigned short*)carve((long long)TOK * DM * 2);
  float*          Ybuf  = (float*)carve((long long)SLOTS * DM * 4);           // aliases qkvLo
  unsigned short* vThi  = (unsigned short*)carve((long long)BAT*NH*64*VPAD*2 + 64);
  unsigned short* vTlo  = (unsigned short*)carve((long long)BAT*NH*64*VPAD*2 + 64);
  unsigned short* wreg  = (unsigned short*)carve(40108032LL * 2);
  unsigned short* wInLo = (unsigned short*)carve((long long)D3*DM*2);
  unsigned short* wOutLo= (unsigned short*)carve((long long)DM*DM*2);
  int*   counts   = (int*)carve(64);
  int*   cur      = (int*)carve(64);
  int*   tileCnt  = (int*)carve(64);
  int4*  tileMap  = (int4*)carve(256 * 16);
  int*   e0 = (int*)carve(TOK*4); int* e1 = (int*)carve(TOK*4);
  float* w0 = (float*)carve(TOK*4); float* w1 = (float*)carve(TOK*4);
  int*   perm  = (int*)carve(SLOTS*4);
  float* wslot = (float*)carve(SLOTS*4);
  int*   slotA = (int*)carve(TOK*4); int* slotB = (int*)carve(TOK*4);
  (void)in_sizes; (void)n_in; (void)out_size; (void)ws_size;

  unsigned short* qkvB  = bigB;
  unsigned short* qkvLo = (unsigned short*)Ybuf;
  unsigned short* Hbuf  = bigB;
  unsigned short* wIn  = wreg;
  unsigned short* wOut = wreg + 1769472;
  unsigned short* wFc1 = wreg + 2359296;
  unsigned short* wFc2 = wreg + 21233664;

  copy_k<<<4096, 256, 0, stream>>>(xout, in_x, (long long)TOK*DM/4);

  for (int layer = 0; layer < 4; ++layer) {
    bool moe = layer < 2;
    bool hp  = (layer == 0);
    int li = moe ? layer : layer - 2;
    const float* ln1s = moe ? p_mln1s + li*DM : p_sln1s + li*DM;
    const float* ln1b = moe ? p_mln1b + li*DM : p_sln1b + li*DM;
    const float* inw  = moe ? p_minw + (long long)li*D3*DM : p_sinw + (long long)li*D3*DM;
    const float* inb  = moe ? p_minb + li*D3 : p_sinb + li*D3;
    const float* outw = moe ? p_moutw + (long long)li*DM*DM : p_soutw + (long long)li*DM*DM;
    const float* outb = moe ? p_moutb + li*DM : p_soutb + li*DM;
    const float* ln2s = moe ? p_mln2s + li*DM : p_sln2s + li*DM;
    const float* ln2b = moe ? p_mln2b + li*DM : p_sln2b + li*DM;

    if (hp) {
      conv2_k<<<2048, 256, 0, stream>>>(wIn, wInLo, inw, (long long)D3*DM/4);
      conv2_k<<<1024, 256, 0, stream>>>(wOut, wOutLo, outw, (long long)DM*DM/4);
    } else {
      conv_k<<<2048, 256, 0, stream>>>(wIn,  inw,  (long long)D3*DM/4);
      conv_k<<<1024, 256, 0, stream>>>(wOut, outw, (long long)DM*DM/4);
    }
    if (moe) {
      conv_k<<<4096, 256, 0, stream>>>(wFc1, p_w1 + (long long)li*NE*FF*DM, (long long)NE*FF*DM/4);
      conv_k<<<4096, 256, 0, stream>>>(wFc2, p_w2 + (long long)li*NE*DM*FF, (long long)NE*DM*FF/4);
    } else {
      conv_k<<<2048, 256, 0, stream>>>(wFc1, p_sfcw   + (long long)li*FF*DM, (long long)FF*DM/4);
      conv_k<<<2048, 256, 0, stream>>>(wFc2, p_sprojw + (long long)li*DM*FF, (long long)DM*FF/4);
    }

    if (hp) {
      ln2bf_k<<<TOK/4, 256, 0, stream>>>(xout, ln1s, ln1b, lnB, lnLo);
      gemm_hp_k<0><<<dim3(D3/128, 99), 256, 0, stream>>>(lnB, lnLo, wIn, wInLo, inb,
          TOK, D3, DM, qkvB, qkvLo, nullptr);
      vtrans_k<<<BAT*NH, 256, 0, stream>>>(qkvB, qkvLo, vThi, vTlo);
      attn_hp_k<<<BAT*NH, 256, 0, stream>>>(qkvB, qkvLo, vThi, vTlo, attnB, attnLo);
      gemm_hp_k<1><<<dim3(DM/128, 99), 256, 0, stream>>>(attnB, attnLo, wOut, wOutLo, outb,
          TOK, DM, DM, nullptr, nullptr, xout);
    } else {
      ln_k<<<TOK/4, 256, 0, stream>>>(xout, ln1s, ln1b, lnB);
      gemm_k<0,false,false><<<dim3(D3/128, 99), 256, 0, stream>>>(lnB, wIn, inb, TOK, D3, DM,
          nullptr, nullptr, nullptr, nullptr, qkvB, nullptr, 0, 0);
      attn_k<<<BAT*NH, 256, 0, stream>>>(qkvB, attnB);
      gemm_k<2,false,false><<<dim3(DM/128, 99), 256, 0, stream>>>(attnB, wOut, outb, TOK, DM, DM,
          nullptr, nullptr, nullptr, nullptr, nullptr, xout, 0, 0);
    }
    ln_k<<<TOK/4, 256, 0, stream>>>(xout, ln2s, ln2b, lnB);

    if (layer == 0) {
      zero_k<<<1, 64, 0, stream>>>(counts, 8);
      gate_k<<<TOK/4, 256, 0, stream>>>(xout, ln2s, ln2b, p_gate, logits, e0, e1, w0, w1);
      hist_k<<<64, 256, 0, stream>>>(e0, e1, counts);
      tilemap_k<<<1, 1, 0, stream>>>(counts, cur, tileMap, tileCnt);
      scatter_k<<<(TOK+255)/256, 256, 0, stream>>>(e0, e1, w0, w1, cur, perm, wslot, slotA, slotB);
    }

    if (moe) {
      gemm_k<1,true,true><<<dim3(FF/128, 205), 256, 0, stream>>>(lnB, wFc1, p_b1 + (long long)li*NE*FF,
          SLOTS, FF, DM, perm, tileMap, tileCnt, nullptr, Hbuf, nullptr, (long long)FF*DM, FF);
      gemm_k<3,true,false><<<dim3(DM/128, 205), 256, 0, stream>>>(Hbuf, wFc2, p_b2 + (long long)li*NE*DM,
          SLOTS, DM, FF, nullptr, tileMap, tileCnt, wslot, nullptr, Ybuf, (long long)DM*FF, DM);
      combine_k<<<TOK*(DM/4)/256, 256, 0, stream>>>(xout, Ybuf, slotA, slotB);
    } else {
      gemm_k<1,false,false><<<dim3(FF/128, 99), 256, 0, stream>>>(lnB, wFc1, p_sfcb + li*FF,
          TOK, FF, DM, nullptr, nullptr, nullptr, nullptr, Hbuf, nullptr, 0, 0);
      gemm_k<2,false,false><<<dim3(DM/128, 99), 256, 0, stream>>>(Hbuf, wFc2, p_sprojb + li*DM,
          TOK, DM, FF, nullptr, nullptr, nullptr, nullptr, nullptr, xout, 0, 0);
    }
  }
}